// Round 7
// baseline (688.950 us; speedup 1.0000x reference)
//
#include <hip/hip_runtime.h>
#include <math.h>

#define S 2048
#define HID 1024
#define NH 16
#define HD 64
#define BH 32   // B * NH

typedef __attribute__((ext_vector_type(8))) short bf16x8;
typedef __attribute__((ext_vector_type(4))) float f32x4;
typedef __attribute__((ext_vector_type(8))) unsigned short ush8;
typedef unsigned short u16;
typedef unsigned int u32;

__device__ __forceinline__ u16 f2bf(float f) {
    unsigned u = __float_as_uint(f);
    u += 0x7fffu + ((u >> 16) & 1u);
    return (u16)(u >> 16);
}
__device__ __forceinline__ float bf2f(u16 h) {
    return __uint_as_float(((unsigned)h) << 16);
}

// ---------------------------------------------------------------------------
// Split fp32 -> (hi, lo) bf16 for X and all four weights in ONE launch.
// ---------------------------------------------------------------------------
__global__ __launch_bounds__(256)
void split_all(const float* __restrict__ X,  const float* __restrict__ Wq,
               const float* __restrict__ Wk, const float* __restrict__ Wv,
               const float* __restrict__ Wo,
               u16* __restrict__ Xh,  u16* __restrict__ Xl,
               u16* __restrict__ Wqh, u16* __restrict__ Wql,
               u16* __restrict__ Wkh, u16* __restrict__ Wkl,
               u16* __restrict__ Wvh, u16* __restrict__ Wvl,
               u16* __restrict__ Woh, u16* __restrict__ Wol)
{
    size_t i = (size_t)blockIdx.x * 256 + threadIdx.x;
    const float* s; u16* h; u16* l; size_t o;
    if (i < (size_t)(1u << 20)) { s = X; h = Xh; l = Xl; o = i; }
    else {
        size_t j = i - (1u << 20);
        int wsel = (int)(j >> 18); o = j & ((1u << 18) - 1);
        s = wsel == 0 ? Wq  : wsel == 1 ? Wk  : wsel == 2 ? Wv  : Wo;
        h = wsel == 0 ? Wqh : wsel == 1 ? Wkh : wsel == 2 ? Wvh : Woh;
        l = wsel == 0 ? Wql : wsel == 1 ? Wkl : wsel == 2 ? Wvl : Wol;
    }
    float4 v = ((const float4*)s)[o];
    ushort4 hv, lv;
#define SP(c, k) { unsigned u = __float_as_uint(v.c);                      \
                   unsigned hb = u & 0xffff0000u;                          \
                   float d = v.c - __uint_as_float(hb);                    \
                   hv.k = (u16)(u >> 16);                                  \
                   lv.k = (u16)(__float_as_uint(d) >> 16); }
    SP(x, x) SP(y, y) SP(z, z) SP(w, w)
#undef SP
    ((ushort4*)h)[o] = hv;
    ((ushort4*)l)[o] = lv;
}

// ---------------------------------------------------------------------------
// Split-precision MFMA GEMM: Y = X @ W^T + b. Output bf16 (b,h,s,d).
// grid (8, 32, 3)
// ---------------------------------------------------------------------------
__global__ __launch_bounds__(256)
void qkv_mfma(const u16* __restrict__ Xh, const u16* __restrict__ Xl,
              const u16* __restrict__ Wh_q, const u16* __restrict__ Wl_q,
              const u16* __restrict__ Wh_k, const u16* __restrict__ Wl_k,
              const u16* __restrict__ Wh_v, const u16* __restrict__ Wl_v,
              const float* __restrict__ bq_, const float* __restrict__ bk_,
              const float* __restrict__ bv_,
              u16* __restrict__ Qb, u16* __restrict__ Kb, u16* __restrict__ Vb)
{
    const int z = blockIdx.z;
    const u16* __restrict__ Wh = z == 0 ? Wh_q : (z == 1 ? Wh_k : Wh_v);
    const u16* __restrict__ Wl = z == 0 ? Wl_q : (z == 1 ? Wl_k : Wl_v);
    const float* __restrict__ bias = z == 0 ? bq_ : (z == 1 ? bk_ : bv_);
    u16* __restrict__ Ob = z == 0 ? Qb : (z == 1 ? Kb : Vb);

    __shared__ u16 Ah[128 * 40], Al[128 * 40], Bh[128 * 40], Bl[128 * 40];
    const int t = threadIdx.x;
    const int m0 = blockIdx.y * 128, n0 = blockIdx.x * 128;
    const int srow = t >> 1, scol = (t & 1) * 16;
    const int lane = t & 63, w = t >> 6, wm = w >> 1, wn = w & 1;
    const int lr = lane & 15, lg = lane >> 4;

    f32x4 acc[4][4] = {{{0.f, 0.f, 0.f, 0.f}}};
    for (int k0 = 0; k0 < HID; k0 += 32) {
        size_t ao = (size_t)(m0 + srow) * HID + k0 + scol;
        size_t bo = (size_t)(n0 + srow) * HID + k0 + scol;
        ush8 a0 = *(const ush8*)(Xh + ao), a1 = *(const ush8*)(Xh + ao + 8);
        ush8 a2 = *(const ush8*)(Xl + ao), a3 = *(const ush8*)(Xl + ao + 8);
        ush8 b0 = *(const ush8*)(Wh + bo), b1 = *(const ush8*)(Wh + bo + 8);
        ush8 b2 = *(const ush8*)(Wl + bo), b3 = *(const ush8*)(Wl + bo + 8);
        __syncthreads();
        *(ush8*)&Ah[srow * 40 + scol] = a0; *(ush8*)&Ah[srow * 40 + scol + 8] = a1;
        *(ush8*)&Al[srow * 40 + scol] = a2; *(ush8*)&Al[srow * 40 + scol + 8] = a3;
        *(ush8*)&Bh[srow * 40 + scol] = b0; *(ush8*)&Bh[srow * 40 + scol + 8] = b1;
        *(ush8*)&Bl[srow * 40 + scol] = b2; *(ush8*)&Bl[srow * 40 + scol + 8] = b3;
        __syncthreads();
        bf16x8 fbh[4], fbl[4];
#pragma unroll
        for (int ni = 0; ni < 4; ++ni) {
            fbh[ni] = *(const bf16x8*)&Bh[(wn * 64 + ni * 16 + lr) * 40 + lg * 8];
            fbl[ni] = *(const bf16x8*)&Bl[(wn * 64 + ni * 16 + lr) * 40 + lg * 8];
        }
#pragma unroll
        for (int mi = 0; mi < 4; ++mi) {
            bf16x8 fah = *(const bf16x8*)&Ah[(wm * 64 + mi * 16 + lr) * 40 + lg * 8];
            bf16x8 fal = *(const bf16x8*)&Al[(wm * 64 + mi * 16 + lr) * 40 + lg * 8];
#pragma unroll
            for (int ni = 0; ni < 4; ++ni) {
                f32x4 c = acc[mi][ni];
                c = __builtin_amdgcn_mfma_f32_16x16x32_bf16(fah, fbh[ni], c, 0, 0, 0);
                c = __builtin_amdgcn_mfma_f32_16x16x32_bf16(fah, fbl[ni], c, 0, 0, 0);
                c = __builtin_amdgcn_mfma_f32_16x16x32_bf16(fal, fbh[ni], c, 0, 0, 0);
                acc[mi][ni] = c;
            }
        }
    }
    const int hh = blockIdx.x * 2 + wn;
    float bv4[4];
#pragma unroll
    for (int ni = 0; ni < 4; ++ni) bv4[ni] = bias[n0 + wn * 64 + ni * 16 + lr];
#pragma unroll
    for (int mi = 0; mi < 4; ++mi)
#pragma unroll
        for (int r = 0; r < 4; ++r) {
            int m = m0 + wm * 64 + mi * 16 + lg * 4 + r;
            int b = m >> 11, s = m & 2047;
#pragma unroll
            for (int ni = 0; ni < 4; ++ni) {
                float v = acc[mi][ni][r] + bv4[ni];
                Ob[((size_t)(b * NH + hh) * S + s) * HD + ni * 16 + lr] = f2bf(v);
            }
        }
}

// ---------------------------------------------------------------------------
// out = OH @ Wo^T + bo (split precision, fp32 out). grid (8, 32)
// ---------------------------------------------------------------------------
__global__ __launch_bounds__(256)
void out_mfma(const u16* __restrict__ Xh, const u16* __restrict__ Xl,
              const u16* __restrict__ Wh, const u16* __restrict__ Wl,
              const float* __restrict__ bo_, float* __restrict__ Y)
{
    __shared__ u16 Ah[128 * 40], Al[128 * 40], Bh[128 * 40], Bl[128 * 40];
    const int t = threadIdx.x;
    const int m0 = blockIdx.y * 128, n0 = blockIdx.x * 128;
    const int srow = t >> 1, scol = (t & 1) * 16;
    const int lane = t & 63, w = t >> 6, wm = w >> 1, wn = w & 1;
    const int lr = lane & 15, lg = lane >> 4;

    f32x4 acc[4][4] = {{{0.f, 0.f, 0.f, 0.f}}};
    for (int k0 = 0; k0 < HID; k0 += 32) {
        size_t ao = (size_t)(m0 + srow) * HID + k0 + scol;
        size_t bo = (size_t)(n0 + srow) * HID + k0 + scol;
        ush8 a0 = *(const ush8*)(Xh + ao), a1 = *(const ush8*)(Xh + ao + 8);
        ush8 a2 = *(const ush8*)(Xl + ao), a3 = *(const ush8*)(Xl + ao + 8);
        ush8 b0 = *(const ush8*)(Wh + bo), b1 = *(const ush8*)(Wh + bo + 8);
        ush8 b2 = *(const ush8*)(Wl + bo), b3 = *(const ush8*)(Wl + bo + 8);
        __syncthreads();
        *(ush8*)&Ah[srow * 40 + scol] = a0; *(ush8*)&Ah[srow * 40 + scol + 8] = a1;
        *(ush8*)&Al[srow * 40 + scol] = a2; *(ush8*)&Al[srow * 40 + scol + 8] = a3;
        *(ush8*)&Bh[srow * 40 + scol] = b0; *(ush8*)&Bh[srow * 40 + scol + 8] = b1;
        *(ush8*)&Bl[srow * 40 + scol] = b2; *(ush8*)&Bl[srow * 40 + scol + 8] = b3;
        __syncthreads();
        bf16x8 fbh[4], fbl[4];
#pragma unroll
        for (int ni = 0; ni < 4; ++ni) {
            fbh[ni] = *(const bf16x8*)&Bh[(wn * 64 + ni * 16 + lr) * 40 + lg * 8];
            fbl[ni] = *(const bf16x8*)&Bl[(wn * 64 + ni * 16 + lr) * 40 + lg * 8];
        }
#pragma unroll
        for (int mi = 0; mi < 4; ++mi) {
            bf16x8 fah = *(const bf16x8*)&Ah[(wm * 64 + mi * 16 + lr) * 40 + lg * 8];
            bf16x8 fal = *(const bf16x8*)&Al[(wm * 64 + mi * 16 + lr) * 40 + lg * 8];
#pragma unroll
            for (int ni = 0; ni < 4; ++ni) {
                f32x4 c = acc[mi][ni];
                c = __builtin_amdgcn_mfma_f32_16x16x32_bf16(fah, fbh[ni], c, 0, 0, 0);
                c = __builtin_amdgcn_mfma_f32_16x16x32_bf16(fah, fbl[ni], c, 0, 0, 0);
                c = __builtin_amdgcn_mfma_f32_16x16x32_bf16(fal, fbh[ni], c, 0, 0, 0);
                acc[mi][ni] = c;
            }
        }
    }
    float bv4[4];
#pragma unroll
    for (int ni = 0; ni < 4; ++ni) bv4[ni] = bo_[n0 + wn * 64 + ni * 16 + lr];
#pragma unroll
    for (int mi = 0; mi < 4; ++mi)
#pragma unroll
        for (int r = 0; r < 4; ++r) {
            int m = m0 + wm * 64 + mi * 16 + lg * 4 + r;
#pragma unroll
            for (int ni = 0; ni < 4; ++ni)
                Y[(size_t)m * HID + n0 + wn * 64 + ni * 16 + lr] =
                    acc[mi][ni][r] + bv4[ni];
        }
}

// ---------------------------------------------------------------------------
// Fused attention, r5 shape + swapped operands + direct-global K.
// grid 512 (r5 XCD map), block 512 = 8 waves, q-tile 128 (16 q/wave), full k.
// Pass A: ZERO barriers — K fragments direct from global, per-lane online
//   (M, Ssum) over the lane's q row (k contiguous in 4s -> int4/float4 loads),
//   merged across the 4 lg lanes with 2 shuffles at the end.
// Pass B: K direct; V^T double-buffered in LDS, ONE barrier per 64-k chunk;
//   recompute scores (identical fragments), write fp32 attn once, PV MFMA.
//   P is wave-local in LDS (no barrier between write and read).
// ---------------------------------------------------------------------------
__global__ __launch_bounds__(512, 4)
void attn_pv(const u16* __restrict__ Qb, const u16* __restrict__ Kb,
             const u16* __restrict__ Vb,
             const int* __restrict__ dist, const float* __restrict__ idf,
             const int* __restrict__ amask, const float* __restrict__ semb,
             const float* __restrict__ rw,
             float* __restrict__ attn, u16* __restrict__ OHh, u16* __restrict__ OHl)
{
    __shared__ u16 Ps[128 * 72];      // P: [q-local 128][64 k + pad]
    __shared__ u16 Vts[2][64 * 72];   // V^T dbuf: [d 64][64 k + pad]
    __shared__ float SeH[51];

    const int n = blockIdx.x;
    const int xcd = n & 7, rest = n >> 3;      // rest 0..63
    const int h = rest & 15;
    const int pair = xcd * 4 + (rest >> 4);    // 0..31; same for all 16 h
    const int b = pair >> 4, qt = pair & 15;
    const int bh = b * NH + h, q0 = qt * 128;

    const int t = threadIdx.x, lane = t & 63, w = t >> 6;
    const int lr = lane & 15, lg = lane >> 4;
    const int q = q0 + w * 16 + lr;            // this lane's q row (QK phase)

    if (t < 51) SeH[t] = semb[t * NH + h];
    __syncthreads();

    // Q fragments direct from global (once)
    const u16* qrow = Qb + ((size_t)bh * S + q) * HD;
    bf16x8 qa0 = *(const bf16x8*)(qrow + lg * 8);
    bf16x8 qa1 = *(const bf16x8*)(qrow + 32 + lg * 8);

    const float rwv = rw[0];
    const float idq = idf[b * S + q];
    const int*   dptr = dist + (size_t)(b * S + q) * S;
    const float* iptr = idf + b * S;
    const int*   mptr = amask + b * S;
    const u16* kbase = Kb + (size_t)bh * S * HD;
    const u16* vbase = Vb + (size_t)bh * S * HD;

    // ---------------- pass A: online row stats, barrier-free ----------------
    float M = -INFINITY, Ssum = 0.f;

    for (int it = 0; it < 32; ++it) {
        const int k0 = it * 64;
        f32x4 c2[4];
#pragma unroll
        for (int ni = 0; ni < 4; ++ni) {
            const u16* krow = kbase + (size_t)(k0 + ni * 16 + lr) * HD;
            bf16x8 kf0 = *(const bf16x8*)(krow + lg * 8);
            bf16x8 kf1 = *(const bf16x8*)(krow + 32 + lg * 8);
            f32x4 c = {0.f, 0.f, 0.f, 0.f};
            c = __builtin_amdgcn_mfma_f32_16x16x32_bf16(kf0, qa0, c, 0, 0, 0);
            c = __builtin_amdgcn_mfma_f32_16x16x32_bf16(kf1, qa1, c, 0, 0, 0);
            c2[ni] = c;
        }

        float sc[4][4];
        float chm = -INFINITY;
#pragma unroll
        for (int ni = 0; ni < 4; ++ni) {
            const int kb = k0 + ni * 16 + lg * 4;
            int4   dv = *(const int4*)(dptr + kb);
            float4 ik = *(const float4*)(iptr + kb);
            int4   mv = *(const int4*)(mptr + kb);
            int   dd[4] = {dv.x, dv.y, dv.z, dv.w};
            float ikf[4] = {ik.x, ik.y, ik.z, ik.w};
            int   mm[4] = {mv.x, mv.y, mv.z, mv.w};
#pragma unroll
            for (int r = 0; r < 4; ++r) {
                int dc = dd[r]; dc = dc < 0 ? 0 : (dc > 50 ? 50 : dc);
                float v = c2[ni][r] * 0.125f + SeH[dc] + rwv * (idq + ikf[r]);
                if (mm[r] == 0) v = -INFINITY;
                sc[ni][r] = v;
                chm = fmaxf(chm, v);
            }
        }
        if (chm > -INFINITY) {
            float mn = fmaxf(M, chm);
            float s = 0.f;
#pragma unroll
            for (int ni = 0; ni < 4; ++ni)
#pragma unroll
                for (int r = 0; r < 4; ++r) s += __expf(sc[ni][r] - mn);
            Ssum = Ssum * __expf(M - mn) + s;
            M = mn;
        }
    }
    // merge the 4 lg lanes of this q row
#pragma unroll
    for (int off = 16; off <= 32; off <<= 1) {
        float Mo = __shfl_xor(M, off), So = __shfl_xor(Ssum, off);
        float mn = fmaxf(M, Mo);
        Ssum = Ssum * __expf(M - mn) + So * __expf(Mo - mn);
        M = mn;
    }
    const float Iv = 1.0f / Ssum;

    // ---------------- pass B: recompute, write attn, PV ----------------
    float* aptr = attn + ((size_t)bh * S + q) * S;
    f32x4 oacc[4] = {{0.f,0.f,0.f,0.f},{0.f,0.f,0.f,0.f},
                     {0.f,0.f,0.f,0.f},{0.f,0.f,0.f,0.f}};

    // V^T staging: thread -> (k row = lane, 8 d = w*8..w*8+7)
    {
        ush8 v0 = *(const ush8*)(vbase + (size_t)lane * HD + w * 8);
#pragma unroll
        for (int j = 0; j < 8; ++j)
            Vts[0][(w * 8 + j) * 72 + lane] = v0[j];
    }
    __syncthreads();

    for (int it = 0; it < 32; ++it) {
        const int k0 = it * 64;
        const int cur = it & 1;
        if (it < 31) {   // stage next chunk into the other buffer
            ush8 v0 = *(const ush8*)(vbase + (size_t)(k0 + 64 + lane) * HD + w * 8);
#pragma unroll
            for (int j = 0; j < 8; ++j)
                Vts[cur ^ 1][(w * 8 + j) * 72 + lane] = v0[j];
        }

        f32x4 c2[4];
#pragma unroll
        for (int ni = 0; ni < 4; ++ni) {
            const u16* krow = kbase + (size_t)(k0 + ni * 16 + lr) * HD;
            bf16x8 kf0 = *(const bf16x8*)(krow + lg * 8);
            bf16x8 kf1 = *(const bf16x8*)(krow + 32 + lg * 8);
            f32x4 c = {0.f, 0.f, 0.f, 0.f};
            c = __builtin_amdgcn_mfma_f32_16x16x32_bf16(kf0, qa0, c, 0, 0, 0);
            c = __builtin_amdgcn_mfma_f32_16x16x32_bf16(kf1, qa1, c, 0, 0, 0);
            c2[ni] = c;
        }

#pragma unroll
        for (int ni = 0; ni < 4; ++ni) {
            const int kb = k0 + ni * 16 + lg * 4;
            int4   dv = *(const int4*)(dptr + kb);
            float4 ik = *(const float4*)(iptr + kb);
            int4   mv = *(const int4*)(mptr + kb);
            int   dd[4] = {dv.x, dv.y, dv.z, dv.w};
            float ikf[4] = {ik.x, ik.y, ik.z, ik.w};
            int   mm[4] = {mv.x, mv.y, mv.z, mv.w};
            float pp[4];
#pragma unroll
            for (int r = 0; r < 4; ++r) {
                int dc = dd[r]; dc = dc < 0 ? 0 : (dc > 50 ? 50 : dc);
                float v = c2[ni][r] * 0.125f + SeH[dc] + rwv * (idq + ikf[r]);
                if (mm[r] == 0) v = -INFINITY;
                pp[r] = __expf(v - M) * Iv;
            }
            *(float4*)(aptr + kb) = make_float4(pp[0], pp[1], pp[2], pp[3]);
            uint2 pk;
            pk.x = (u32)f2bf(pp[0]) | ((u32)f2bf(pp[1]) << 16);
            pk.y = (u32)f2bf(pp[2]) | ((u32)f2bf(pp[3]) << 16);
            *(uint2*)&Ps[(w * 16 + lr) * 72 + ni * 16 + lg * 4] = pk;
        }

        // PV: wave-local P rows (this wave wrote them; LDS ops in-order)
        bf16x8 pa0 = *(const bf16x8*)&Ps[(w * 16 + lr) * 72 + lg * 8];
        bf16x8 pa1 = *(const bf16x8*)&Ps[(w * 16 + lr) * 72 + 32 + lg * 8];
        __builtin_amdgcn_s_setprio(1);
#pragma unroll
        for (int ni = 0; ni < 4; ++ni) {
            bf16x8 vb0 = *(const bf16x8*)&Vts[cur][(ni * 16 + lr) * 72 + lg * 8];
            bf16x8 vb1 = *(const bf16x8*)&Vts[cur][(ni * 16 + lr) * 72 + 32 + lg * 8];
            oacc[ni] = __builtin_amdgcn_mfma_f32_16x16x32_bf16(pa0, vb0, oacc[ni], 0, 0, 0);
            oacc[ni] = __builtin_amdgcn_mfma_f32_16x16x32_bf16(pa1, vb1, oacc[ni], 0, 0, 0);
        }
        __builtin_amdgcn_s_setprio(0);
        __syncthreads();   // next-chunk V staged by all; prev reads done
    }

    // OH epilogue: PV output is [q-local = lg*4+r][d = ni*16+lr]
#pragma unroll
    for (int r = 0; r < 4; ++r) {
        const int qq = q0 + w * 16 + lg * 4 + r;
#pragma unroll
        for (int ni = 0; ni < 4; ++ni) {
            float v = oacc[ni][r];
            u16 hi = f2bf(v);
            u16 lo = f2bf(v - bf2f(hi));
            size_t off = ((size_t)b * S + qq) * HID + h * HD + ni * 16 + lr;
            OHh[off] = hi;
            OHl[off] = lo;
        }
    }
}

// ---------------------------------------------------------------------------
extern "C" void kernel_launch(void* const* d_in, const int* in_sizes, int n_in,
                              void* d_out, int out_size, void* d_ws, size_t ws_size,
                              hipStream_t stream)
{
    const float* hs   = (const float*)d_in[0];
    const int*   dist = (const int*)d_in[1];
    const float* idf  = (const float*)d_in[2];
    const int*   am   = (const int*)d_in[3];
    const float* Wq   = (const float*)d_in[4];
    const float* bq   = (const float*)d_in[5];
    const float* Wk   = (const float*)d_in[6];
    const float* bk   = (const float*)d_in[7];
    const float* Wv   = (const float*)d_in[8];
    const float* bv   = (const float*)d_in[9];
    const float* Wo   = (const float*)d_in[10];
    const float* bo   = (const float*)d_in[11];
    const float* se   = (const float*)d_in[12];
    const float* rw   = (const float*)d_in[13];

    float* out  = (float*)d_out;
    float* attn = out + (size_t)2 * S * HID;

    // X hi/lo hide in the (not yet written) attn output region
    u16* Xh = (u16*)attn;
    u16* Xl = Xh + (size_t)4096 * 1024;

    // workspace layout
    u16* Qb  = (u16*)d_ws;
    u16* Kb  = Qb  + (size_t)BH * S * HD;
    u16* Vb  = Kb  + (size_t)BH * S * HD;
    u16* OHh = Vb  + (size_t)BH * S * HD;
    u16* OHl = OHh + (size_t)4096 * 1024;
    u16* Woh = OHl + (size_t)4096 * 1024;
    u16* Wol = Woh + (size_t)1024 * 1024;
    u16* Wqh = Wol + (size_t)1024 * 1024;
    u16* Wql = Wqh + (size_t)1024 * 1024;
    u16* Wkh = Wql + (size_t)1024 * 1024;
    u16* Wkl = Wkh + (size_t)1024 * 1024;
    u16* Wvh = Wkl + (size_t)1024 * 1024;
    u16* Wvl = Wvh + (size_t)1024 * 1024;

    dim3 blk(256);
    split_all<<<dim3(8192), blk, 0, stream>>>(hs, Wq, Wk, Wv, Wo,
                                              Xh, Xl, Wqh, Wql, Wkh, Wkl,
                                              Wvh, Wvl, Woh, Wol);
    qkv_mfma<<<dim3(8, 32, 3), blk, 0, stream>>>(Xh, Xl, Wqh, Wql, Wkh, Wkl,
                                                 Wvh, Wvl, bq, bk, bv, Qb, Kb, Vb);
    attn_pv<<<dim3(512), dim3(512), 0, stream>>>(Qb, Kb, Vb, dist, idf, am, se, rw,
                                                 attn, OHh, OHl);
    out_mfma<<<dim3(8, 32), blk, 0, stream>>>(OHh, OHl, Woh, Wol, bo, out);
}

// Round 8
// 554.902 us; speedup vs baseline: 1.2416x; 1.2416x over previous
//
#include <hip/hip_runtime.h>
#include <math.h>

#define S 2048
#define HID 1024
#define NH 16
#define HD 64
#define BH 32   // B * NH

typedef __attribute__((ext_vector_type(8))) short bf16x8;
typedef __attribute__((ext_vector_type(4))) float f32x4;
typedef __attribute__((ext_vector_type(8))) unsigned short ush8;
typedef unsigned short u16;
typedef unsigned int u32;

__device__ __forceinline__ u16 f2bf(float f) {
    unsigned u = __float_as_uint(f);
    u += 0x7fffu + ((u >> 16) & 1u);
    return (u16)(u >> 16);
}
__device__ __forceinline__ float bf2f(u16 h) {
    return __uint_as_float(((unsigned)h) << 16);
}

// ---------------------------------------------------------------------------
// Split fp32 -> (hi, lo) bf16 for X and all four weights in ONE launch.
// ---------------------------------------------------------------------------
__global__ __launch_bounds__(256)
void split_all(const float* __restrict__ X,  const float* __restrict__ Wq,
               const float* __restrict__ Wk, const float* __restrict__ Wv,
               const float* __restrict__ Wo,
               u16* __restrict__ Xh,  u16* __restrict__ Xl,
               u16* __restrict__ Wqh, u16* __restrict__ Wql,
               u16* __restrict__ Wkh, u16* __restrict__ Wkl,
               u16* __restrict__ Wvh, u16* __restrict__ Wvl,
               u16* __restrict__ Woh, u16* __restrict__ Wol)
{
    size_t i = (size_t)blockIdx.x * 256 + threadIdx.x;
    const float* s; u16* h; u16* l; size_t o;
    if (i < (size_t)(1u << 20)) { s = X; h = Xh; l = Xl; o = i; }
    else {
        size_t j = i - (1u << 20);
        int wsel = (int)(j >> 18); o = j & ((1u << 18) - 1);
        s = wsel == 0 ? Wq  : wsel == 1 ? Wk  : wsel == 2 ? Wv  : Wo;
        h = wsel == 0 ? Wqh : wsel == 1 ? Wkh : wsel == 2 ? Wvh : Woh;
        l = wsel == 0 ? Wql : wsel == 1 ? Wkl : wsel == 2 ? Wvl : Wol;
    }
    float4 v = ((const float4*)s)[o];
    ushort4 hv, lv;
#define SP(c, k) { unsigned u = __float_as_uint(v.c);                      \
                   unsigned hb = u & 0xffff0000u;                          \
                   float d = v.c - __uint_as_float(hb);                    \
                   hv.k = (u16)(u >> 16);                                  \
                   lv.k = (u16)(__float_as_uint(d) >> 16); }
    SP(x, x) SP(y, y) SP(z, z) SP(w, w)
#undef SP
    ((ushort4*)h)[o] = hv;
    ((ushort4*)l)[o] = lv;
}

// ---------------------------------------------------------------------------
// Split-precision MFMA GEMM: Y = X @ W^T + b. Output bf16 (b,h,s,d).
// grid (8, 32, 3)
// ---------------------------------------------------------------------------
__global__ __launch_bounds__(256)
void qkv_mfma(const u16* __restrict__ Xh, const u16* __restrict__ Xl,
              const u16* __restrict__ Wh_q, const u16* __restrict__ Wl_q,
              const u16* __restrict__ Wh_k, const u16* __restrict__ Wl_k,
              const u16* __restrict__ Wh_v, const u16* __restrict__ Wl_v,
              const float* __restrict__ bq_, const float* __restrict__ bk_,
              const float* __restrict__ bv_,
              u16* __restrict__ Qb, u16* __restrict__ Kb, u16* __restrict__ Vb)
{
    const int z = blockIdx.z;
    const u16* __restrict__ Wh = z == 0 ? Wh_q : (z == 1 ? Wh_k : Wh_v);
    const u16* __restrict__ Wl = z == 0 ? Wl_q : (z == 1 ? Wl_k : Wl_v);
    const float* __restrict__ bias = z == 0 ? bq_ : (z == 1 ? bk_ : bv_);
    u16* __restrict__ Ob = z == 0 ? Qb : (z == 1 ? Kb : Vb);

    __shared__ u16 Ah[128 * 40], Al[128 * 40], Bh[128 * 40], Bl[128 * 40];
    const int t = threadIdx.x;
    const int m0 = blockIdx.y * 128, n0 = blockIdx.x * 128;
    const int srow = t >> 1, scol = (t & 1) * 16;
    const int lane = t & 63, w = t >> 6, wm = w >> 1, wn = w & 1;
    const int lr = lane & 15, lg = lane >> 4;

    f32x4 acc[4][4] = {{{0.f, 0.f, 0.f, 0.f}}};
    for (int k0 = 0; k0 < HID; k0 += 32) {
        size_t ao = (size_t)(m0 + srow) * HID + k0 + scol;
        size_t bo = (size_t)(n0 + srow) * HID + k0 + scol;
        ush8 a0 = *(const ush8*)(Xh + ao), a1 = *(const ush8*)(Xh + ao + 8);
        ush8 a2 = *(const ush8*)(Xl + ao), a3 = *(const ush8*)(Xl + ao + 8);
        ush8 b0 = *(const ush8*)(Wh + bo), b1 = *(const ush8*)(Wh + bo + 8);
        ush8 b2 = *(const ush8*)(Wl + bo), b3 = *(const ush8*)(Wl + bo + 8);
        __syncthreads();
        *(ush8*)&Ah[srow * 40 + scol] = a0; *(ush8*)&Ah[srow * 40 + scol + 8] = a1;
        *(ush8*)&Al[srow * 40 + scol] = a2; *(ush8*)&Al[srow * 40 + scol + 8] = a3;
        *(ush8*)&Bh[srow * 40 + scol] = b0; *(ush8*)&Bh[srow * 40 + scol + 8] = b1;
        *(ush8*)&Bl[srow * 40 + scol] = b2; *(ush8*)&Bl[srow * 40 + scol + 8] = b3;
        __syncthreads();
        bf16x8 fbh[4], fbl[4];
#pragma unroll
        for (int ni = 0; ni < 4; ++ni) {
            fbh[ni] = *(const bf16x8*)&Bh[(wn * 64 + ni * 16 + lr) * 40 + lg * 8];
            fbl[ni] = *(const bf16x8*)&Bl[(wn * 64 + ni * 16 + lr) * 40 + lg * 8];
        }
#pragma unroll
        for (int mi = 0; mi < 4; ++mi) {
            bf16x8 fah = *(const bf16x8*)&Ah[(wm * 64 + mi * 16 + lr) * 40 + lg * 8];
            bf16x8 fal = *(const bf16x8*)&Al[(wm * 64 + mi * 16 + lr) * 40 + lg * 8];
#pragma unroll
            for (int ni = 0; ni < 4; ++ni) {
                f32x4 c = acc[mi][ni];
                c = __builtin_amdgcn_mfma_f32_16x16x32_bf16(fah, fbh[ni], c, 0, 0, 0);
                c = __builtin_amdgcn_mfma_f32_16x16x32_bf16(fah, fbl[ni], c, 0, 0, 0);
                c = __builtin_amdgcn_mfma_f32_16x16x32_bf16(fal, fbh[ni], c, 0, 0, 0);
                acc[mi][ni] = c;
            }
        }
    }
    const int hh = blockIdx.x * 2 + wn;
    float bv4[4];
#pragma unroll
    for (int ni = 0; ni < 4; ++ni) bv4[ni] = bias[n0 + wn * 64 + ni * 16 + lr];
#pragma unroll
    for (int mi = 0; mi < 4; ++mi)
#pragma unroll
        for (int r = 0; r < 4; ++r) {
            int m = m0 + wm * 64 + mi * 16 + lg * 4 + r;
            int b = m >> 11, s = m & 2047;
#pragma unroll
            for (int ni = 0; ni < 4; ++ni) {
                float v = acc[mi][ni][r] + bv4[ni];
                Ob[((size_t)(b * NH + hh) * S + s) * HD + ni * 16 + lr] = f2bf(v);
            }
        }
}

// ---------------------------------------------------------------------------
// out = OH @ Wo^T + bo (split precision, fp32 out). grid (8, 32)
// ---------------------------------------------------------------------------
__global__ __launch_bounds__(256)
void out_mfma(const u16* __restrict__ Xh, const u16* __restrict__ Xl,
              const u16* __restrict__ Wh, const u16* __restrict__ Wl,
              const float* __restrict__ bo_, float* __restrict__ Y)
{
    __shared__ u16 Ah[128 * 40], Al[128 * 40], Bh[128 * 40], Bl[128 * 40];
    const int t = threadIdx.x;
    const int m0 = blockIdx.y * 128, n0 = blockIdx.x * 128;
    const int srow = t >> 1, scol = (t & 1) * 16;
    const int lane = t & 63, w = t >> 6, wm = w >> 1, wn = w & 1;
    const int lr = lane & 15, lg = lane >> 4;

    f32x4 acc[4][4] = {{{0.f, 0.f, 0.f, 0.f}}};
    for (int k0 = 0; k0 < HID; k0 += 32) {
        size_t ao = (size_t)(m0 + srow) * HID + k0 + scol;
        size_t bo = (size_t)(n0 + srow) * HID + k0 + scol;
        ush8 a0 = *(const ush8*)(Xh + ao), a1 = *(const ush8*)(Xh + ao + 8);
        ush8 a2 = *(const ush8*)(Xl + ao), a3 = *(const ush8*)(Xl + ao + 8);
        ush8 b0 = *(const ush8*)(Wh + bo), b1 = *(const ush8*)(Wh + bo + 8);
        ush8 b2 = *(const ush8*)(Wl + bo), b3 = *(const ush8*)(Wl + bo + 8);
        __syncthreads();
        *(ush8*)&Ah[srow * 40 + scol] = a0; *(ush8*)&Ah[srow * 40 + scol + 8] = a1;
        *(ush8*)&Al[srow * 40 + scol] = a2; *(ush8*)&Al[srow * 40 + scol + 8] = a3;
        *(ush8*)&Bh[srow * 40 + scol] = b0; *(ush8*)&Bh[srow * 40 + scol + 8] = b1;
        *(ush8*)&Bl[srow * 40 + scol] = b2; *(ush8*)&Bl[srow * 40 + scol + 8] = b3;
        __syncthreads();
        bf16x8 fbh[4], fbl[4];
#pragma unroll
        for (int ni = 0; ni < 4; ++ni) {
            fbh[ni] = *(const bf16x8*)&Bh[(wn * 64 + ni * 16 + lr) * 40 + lg * 8];
            fbl[ni] = *(const bf16x8*)&Bl[(wn * 64 + ni * 16 + lr) * 40 + lg * 8];
        }
#pragma unroll
        for (int mi = 0; mi < 4; ++mi) {
            bf16x8 fah = *(const bf16x8*)&Ah[(wm * 64 + mi * 16 + lr) * 40 + lg * 8];
            bf16x8 fal = *(const bf16x8*)&Al[(wm * 64 + mi * 16 + lr) * 40 + lg * 8];
#pragma unroll
            for (int ni = 0; ni < 4; ++ni) {
                f32x4 c = acc[mi][ni];
                c = __builtin_amdgcn_mfma_f32_16x16x32_bf16(fah, fbh[ni], c, 0, 0, 0);
                c = __builtin_amdgcn_mfma_f32_16x16x32_bf16(fah, fbl[ni], c, 0, 0, 0);
                c = __builtin_amdgcn_mfma_f32_16x16x32_bf16(fal, fbh[ni], c, 0, 0, 0);
                acc[mi][ni] = c;
            }
        }
    }
    float bv4[4];
#pragma unroll
    for (int ni = 0; ni < 4; ++ni) bv4[ni] = bo_[n0 + wn * 64 + ni * 16 + lr];
#pragma unroll
    for (int mi = 0; mi < 4; ++mi)
#pragma unroll
        for (int r = 0; r < 4; ++r) {
            int m = m0 + wm * 64 + mi * 16 + lg * 4 + r;
#pragma unroll
            for (int ni = 0; ni < 4; ++ni)
                Y[(size_t)m * HID + n0 + wn * 64 + ni * 16 + lr] =
                    acc[mi][ni][r] + bv4[ni];
        }
}

// ---------------------------------------------------------------------------
// Fused attention: r5 shape (grid 512, 8 waves, q-tile 128, LDS-staged K/V)
// + swapped-operand vectorized epilogue + single-barrier dbuf + T14 split
// (issue global loads early, ds_write late, 1 barrier/chunk).
// Wave w owns q rows q0 + w*16 + lr; lane (lr,lg) covers k = ni*16+lg*4+..
// Pass A: online per-lane (M,Ssum); merged with 2 shuffles at the end.
// Pass B: recompute (identical fragments), write fp32 attn once, PV MFMA;
//   P wave-local in LDS (no barrier between write and read).
// ---------------------------------------------------------------------------
__global__ __launch_bounds__(512, 4)
void attn_pv(const u16* __restrict__ Qb, const u16* __restrict__ Kb,
             const u16* __restrict__ Vb,
             const int* __restrict__ dist, const float* __restrict__ idf,
             const int* __restrict__ amask, const float* __restrict__ semb,
             const float* __restrict__ rw,
             float* __restrict__ attn, u16* __restrict__ OHh, u16* __restrict__ OHl)
{
    __shared__ u16 Ks[2][64 * 72];    // K dbuf: [k 64][64 d + pad]
    __shared__ u16 Vts[2][64 * 72];   // V^T dbuf: [d 64][64 k + pad]
    __shared__ u16 Ps[128 * 72];      // P: [q-local 128][64 k + pad]
    __shared__ float SeH[51];

    const int n = blockIdx.x;
    const int xcd = n & 7, rest = n >> 3;      // rest 0..63
    const int h = rest & 15;
    const int pair = xcd * 4 + (rest >> 4);    // 0..31; same for all 16 h
    const int b = pair >> 4, qt = pair & 15;
    const int bh = b * NH + h, q0 = qt * 128;

    const int t = threadIdx.x, lane = t & 63, w = t >> 6;
    const int lr = lane & 15, lg = lane >> 4;
    const int q = q0 + w * 16 + lr;            // this lane's q row

    const int sr = t >> 3, sc = (t & 7) * 8;   // K staging: row, col (u16)

    if (t < 51) SeH[t] = semb[t * NH + h];

    // Q fragments direct from global (once; q rows are block-contiguous)
    const u16* qrow = Qb + ((size_t)bh * S + q) * HD;
    bf16x8 qa0 = *(const bf16x8*)(qrow + lg * 8);
    bf16x8 qa1 = *(const bf16x8*)(qrow + 32 + lg * 8);

    const float rwv = rw[0];
    const float idq = idf[b * S + q];
    const int*   dptr = dist + (size_t)(b * S + q) * S;
    const float* iptr = idf + b * S;
    const int*   mptr = amask + b * S;
    const u16* kbase = Kb + (size_t)bh * S * HD;
    const u16* vbase = Vb + (size_t)bh * S * HD;

    // ---------------- pass A: online row stats ----------------
    float M = -INFINITY, Ssum = 0.f;

    // prologue: stage K chunk 0
    *(ush8*)&Ks[0][sr * 72 + sc] = *(const ush8*)(kbase + (size_t)sr * HD + sc);
    __syncthreads();

    for (int it = 0; it < 32; ++it) {
        const int k0 = it * 64;
        const int cur = it & 1;

        ush8 kreg;
        if (it < 31)   // T14: issue next-chunk load early
            kreg = *(const ush8*)(kbase + (size_t)(k0 + 64 + sr) * HD + sc);

        f32x4 c2[4];
        __builtin_amdgcn_s_setprio(1);
#pragma unroll
        for (int ni = 0; ni < 4; ++ni) {
            bf16x8 kf0 = *(const bf16x8*)&Ks[cur][(ni * 16 + lr) * 72 + lg * 8];
            bf16x8 kf1 = *(const bf16x8*)&Ks[cur][(ni * 16 + lr) * 72 + 32 + lg * 8];
            f32x4 c = {0.f, 0.f, 0.f, 0.f};
            c = __builtin_amdgcn_mfma_f32_16x16x32_bf16(kf0, qa0, c, 0, 0, 0);
            c = __builtin_amdgcn_mfma_f32_16x16x32_bf16(kf1, qa1, c, 0, 0, 0);
            c2[ni] = c;
        }
        __builtin_amdgcn_s_setprio(0);

        float sc4[4][4];
        float chm = -INFINITY;
#pragma unroll
        for (int ni = 0; ni < 4; ++ni) {
            const int kb = k0 + ni * 16 + lg * 4;
            int4   dv = *(const int4*)(dptr + kb);
            float4 ik = *(const float4*)(iptr + kb);
            int4   mv = *(const int4*)(mptr + kb);
            int   dd[4] = {dv.x, dv.y, dv.z, dv.w};
            float ikf[4] = {ik.x, ik.y, ik.z, ik.w};
            int   mm[4] = {mv.x, mv.y, mv.z, mv.w};
#pragma unroll
            for (int r = 0; r < 4; ++r) {
                int dc = dd[r]; dc = dc < 0 ? 0 : (dc > 50 ? 50 : dc);
                float v = c2[ni][r] * 0.125f + SeH[dc] + rwv * (idq + ikf[r]);
                if (mm[r] == 0) v = -INFINITY;
                sc4[ni][r] = v;
                chm = fmaxf(chm, v);
            }
        }
        if (chm > -INFINITY) {
            float mn = fmaxf(M, chm);
            float s = 0.f;
#pragma unroll
            for (int ni = 0; ni < 4; ++ni)
#pragma unroll
                for (int r = 0; r < 4; ++r) s += __expf(sc4[ni][r] - mn);
            Ssum = Ssum * __expf(M - mn) + s;
            M = mn;
        }

        if (it < 31)   // T14: write staged regs late
            *(ush8*)&Ks[cur ^ 1][sr * 72 + sc] = kreg;
        __syncthreads();
    }
    // merge the 4 lg lanes of this q row
#pragma unroll
    for (int off = 16; off <= 32; off <<= 1) {
        float Mo = __shfl_xor(M, off), So = __shfl_xor(Ssum, off);
        float mn = fmaxf(M, Mo);
        Ssum = Ssum * __expf(M - mn) + So * __expf(Mo - mn);
        M = mn;
    }
    const float Iv = 1.0f / Ssum;

    // ---------------- pass B: recompute, write attn, PV ----------------
    float* aptr = attn + ((size_t)bh * S + q) * S;
    f32x4 oacc[4] = {{0.f,0.f,0.f,0.f},{0.f,0.f,0.f,0.f},
                     {0.f,0.f,0.f,0.f},{0.f,0.f,0.f,0.f}};

    // prologue: stage K+V chunk 0
    {
        *(ush8*)&Ks[0][sr * 72 + sc] = *(const ush8*)(kbase + (size_t)sr * HD + sc);
        ush8 v0 = *(const ush8*)(vbase + (size_t)lane * HD + w * 8);
#pragma unroll
        for (int j = 0; j < 8; ++j)
            Vts[0][(w * 8 + j) * 72 + lane] = v0[j];
    }
    __syncthreads();

    for (int it = 0; it < 32; ++it) {
        const int k0 = it * 64;
        const int cur = it & 1;

        ush8 kreg, vreg;
        if (it < 31) {   // T14: issue next-chunk loads early
            kreg = *(const ush8*)(kbase + (size_t)(k0 + 64 + sr) * HD + sc);
            vreg = *(const ush8*)(vbase + (size_t)(k0 + 64 + lane) * HD + w * 8);
        }

        f32x4 c2[4];
        __builtin_amdgcn_s_setprio(1);
#pragma unroll
        for (int ni = 0; ni < 4; ++ni) {
            bf16x8 kf0 = *(const bf16x8*)&Ks[cur][(ni * 16 + lr) * 72 + lg * 8];
            bf16x8 kf1 = *(const bf16x8*)&Ks[cur][(ni * 16 + lr) * 72 + 32 + lg * 8];
            f32x4 c = {0.f, 0.f, 0.f, 0.f};
            c = __builtin_amdgcn_mfma_f32_16x16x32_bf16(kf0, qa0, c, 0, 0, 0);
            c = __builtin_amdgcn_mfma_f32_16x16x32_bf16(kf1, qa1, c, 0, 0, 0);
            c2[ni] = c;
        }
        __builtin_amdgcn_s_setprio(0);

#pragma unroll
        for (int ni = 0; ni < 4; ++ni) {
            const int kb = k0 + ni * 16 + lg * 4;
            int4   dv = *(const int4*)(dptr + kb);
            float4 ik = *(const float4*)(iptr + kb);
            int4   mv = *(const int4*)(mptr + kb);
            int   dd[4] = {dv.x, dv.y, dv.z, dv.w};
            float ikf[4] = {ik.x, ik.y, ik.z, ik.w};
            int   mm[4] = {mv.x, mv.y, mv.z, mv.w};
            float pp[4];
#pragma unroll
            for (int r = 0; r < 4; ++r) {
                int dc = dd[r]; dc = dc < 0 ? 0 : (dc > 50 ? 50 : dc);
                float v = c2[ni][r] * 0.125f + SeH[dc] + rwv * (idq + ikf[r]);
                if (mm[r] == 0) v = -INFINITY;
                pp[r] = __expf(v - M) * Iv;
            }
            *(float4*)(aptr + kb) = make_float4(pp[0], pp[1], pp[2], pp[3]);
            uint2 pk;
            pk.x = (u32)f2bf(pp[0]) | ((u32)f2bf(pp[1]) << 16);
            pk.y = (u32)f2bf(pp[2]) | ((u32)f2bf(pp[3]) << 16);
            *(uint2*)&Ps[(w * 16 + lr) * 72 + ni * 16 + lg * 4] = pk;
        }

        // PV: wave-local P rows (this wave wrote them; LDS ops in-order)
        bf16x8 pa0 = *(const bf16x8*)&Ps[(w * 16 + lr) * 72 + lg * 8];
        bf16x8 pa1 = *(const bf16x8*)&Ps[(w * 16 + lr) * 72 + 32 + lg * 8];
        __builtin_amdgcn_s_setprio(1);
#pragma unroll
        for (int ni = 0; ni < 4; ++ni) {
            bf16x8 vb0 = *(const bf16x8*)&Vts[cur][(ni * 16 + lr) * 72 + lg * 8];
            bf16x8 vb1 = *(const bf16x8*)&Vts[cur][(ni * 16 + lr) * 72 + 32 + lg * 8];
            oacc[ni] = __builtin_amdgcn_mfma_f32_16x16x32_bf16(pa0, vb0, oacc[ni], 0, 0, 0);
            oacc[ni] = __builtin_amdgcn_mfma_f32_16x16x32_bf16(pa1, vb1, oacc[ni], 0, 0, 0);
        }
        __builtin_amdgcn_s_setprio(0);

        if (it < 31) {   // T14: write staged regs late
            *(ush8*)&Ks[cur ^ 1][sr * 72 + sc] = kreg;
#pragma unroll
            for (int j = 0; j < 8; ++j)
                Vts[cur ^ 1][(w * 8 + j) * 72 + lane] = vreg[j];
        }
        __syncthreads();
    }

    // OH epilogue: PV output is [q-local = lg*4+r][d = ni*16+lr]
#pragma unroll
    for (int r = 0; r < 4; ++r) {
        const int qq = q0 + w * 16 + lg * 4 + r;
#pragma unroll
        for (int ni = 0; ni < 4; ++ni) {
            float v = oacc[ni][r];
            u16 hi = f2bf(v);
            u16 lo = f2bf(v - bf2f(hi));
            size_t off = ((size_t)b * S + qq) * HID + h * HD + ni * 16 + lr;
            OHh[off] = hi;
            OHl[off] = lo;
        }
    }
}

// ---------------------------------------------------------------------------
extern "C" void kernel_launch(void* const* d_in, const int* in_sizes, int n_in,
                              void* d_out, int out_size, void* d_ws, size_t ws_size,
                              hipStream_t stream)
{
    const float* hs   = (const float*)d_in[0];
    const int*   dist = (const int*)d_in[1];
    const float* idf  = (const float*)d_in[2];
    const int*   am   = (const int*)d_in[3];
    const float* Wq   = (const float*)d_in[4];
    const float* bq   = (const float*)d_in[5];
    const float* Wk   = (const float*)d_in[6];
    const float* bk   = (const float*)d_in[7];
    const float* Wv   = (const float*)d_in[8];
    const float* bv   = (const float*)d_in[9];
    const float* Wo   = (const float*)d_in[10];
    const float* bo   = (const float*)d_in[11];
    const float* se   = (const float*)d_in[12];
    const float* rw   = (const float*)d_in[13];

    float* out  = (float*)d_out;
    float* attn = out + (size_t)2 * S * HID;

    // X hi/lo hide in the (not yet written) attn output region
    u16* Xh = (u16*)attn;
    u16* Xl = Xh + (size_t)4096 * 1024;

    // workspace layout
    u16* Qb  = (u16*)d_ws;
    u16* Kb  = Qb  + (size_t)BH * S * HD;
    u16* Vb  = Kb  + (size_t)BH * S * HD;
    u16* OHh = Vb  + (size_t)BH * S * HD;
    u16* OHl = OHh + (size_t)4096 * 1024;
    u16* Woh = OHl + (size_t)4096 * 1024;
    u16* Wol = Woh + (size_t)1024 * 1024;
    u16* Wqh = Wol + (size_t)1024 * 1024;
    u16* Wql = Wqh + (size_t)1024 * 1024;
    u16* Wkh = Wql + (size_t)1024 * 1024;
    u16* Wkl = Wkh + (size_t)1024 * 1024;
    u16* Wvh = Wkl + (size_t)1024 * 1024;
    u16* Wvl = Wvh + (size_t)1024 * 1024;

    dim3 blk(256);
    split_all<<<dim3(8192), blk, 0, stream>>>(hs, Wq, Wk, Wv, Wo,
                                              Xh, Xl, Wqh, Wql, Wkh, Wkl,
                                              Wvh, Wvl, Woh, Wol);
    qkv_mfma<<<dim3(8, 32, 3), blk, 0, stream>>>(Xh, Xl, Wqh, Wql, Wkh, Wkl,
                                                 Wvh, Wvl, bq, bk, bv, Qb, Kb, Vb);
    attn_pv<<<dim3(512), dim3(512), 0, stream>>>(Qb, Kb, Vb, dist, idf, am, se, rw,
                                                 attn, OHh, OHl);
    out_mfma<<<dim3(8, 32), blk, 0, stream>>>(OHh, OHl, Woh, Wol, bo, out);
}

// Round 9
// 430.383 us; speedup vs baseline: 1.6008x; 1.2893x over previous
//
#include <hip/hip_runtime.h>
#include <math.h>

#define S 2048
#define HID 1024
#define NH 16
#define HD 64
#define BH 32   // B * NH

typedef __attribute__((ext_vector_type(8))) short bf16x8;
typedef __attribute__((ext_vector_type(4))) float f32x4;
typedef __attribute__((ext_vector_type(8))) unsigned short ush8;
typedef unsigned short u16;
typedef unsigned int u32;

__device__ __forceinline__ u16 f2bf(float f) {
    unsigned u = __float_as_uint(f);
    u += 0x7fffu + ((u >> 16) & 1u);
    return (u16)(u >> 16);
}
__device__ __forceinline__ float bf2f(u16 h) {
    return __uint_as_float(((unsigned)h) << 16);
}

// ---------------------------------------------------------------------------
// Split fp32 -> (hi, lo) bf16 for X and all four weights in ONE launch.
// ---------------------------------------------------------------------------
__global__ __launch_bounds__(256)
void split_all(const float* __restrict__ X,  const float* __restrict__ Wq,
               const float* __restrict__ Wk, const float* __restrict__ Wv,
               const float* __restrict__ Wo,
               u16* __restrict__ Xh,  u16* __restrict__ Xl,
               u16* __restrict__ Wqh, u16* __restrict__ Wql,
               u16* __restrict__ Wkh, u16* __restrict__ Wkl,
               u16* __restrict__ Wvh, u16* __restrict__ Wvl,
               u16* __restrict__ Woh, u16* __restrict__ Wol)
{
    size_t i = (size_t)blockIdx.x * 256 + threadIdx.x;
    const float* s; u16* h; u16* l; size_t o;
    if (i < (size_t)(1u << 20)) { s = X; h = Xh; l = Xl; o = i; }
    else {
        size_t j = i - (1u << 20);
        int wsel = (int)(j >> 18); o = j & ((1u << 18) - 1);
        s = wsel == 0 ? Wq  : wsel == 1 ? Wk  : wsel == 2 ? Wv  : Wo;
        h = wsel == 0 ? Wqh : wsel == 1 ? Wkh : wsel == 2 ? Wvh : Woh;
        l = wsel == 0 ? Wql : wsel == 1 ? Wkl : wsel == 2 ? Wvl : Wol;
    }
    float4 v = ((const float4*)s)[o];
    ushort4 hv, lv;
#define SP(c, k) { unsigned u = __float_as_uint(v.c);                      \
                   unsigned hb = u & 0xffff0000u;                          \
                   float d = v.c - __uint_as_float(hb);                    \
                   hv.k = (u16)(u >> 16);                                  \
                   lv.k = (u16)(__float_as_uint(d) >> 16); }
    SP(x, x) SP(y, y) SP(z, z) SP(w, w)
#undef SP
    ((ushort4*)h)[o] = hv;
    ((ushort4*)l)[o] = lv;
}

// ---------------------------------------------------------------------------
// Split-precision MFMA GEMM: Y = X @ W^T + b. Output bf16 (b,h,s,d).
// Q is pre-scaled by 0.125 (exact power-of-2, same bf16 rounding).
// grid (8, 32, 3)
// ---------------------------------------------------------------------------
__global__ __launch_bounds__(256)
void qkv_mfma(const u16* __restrict__ Xh, const u16* __restrict__ Xl,
              const u16* __restrict__ Wh_q, const u16* __restrict__ Wl_q,
              const u16* __restrict__ Wh_k, const u16* __restrict__ Wl_k,
              const u16* __restrict__ Wh_v, const u16* __restrict__ Wl_v,
              const float* __restrict__ bq_, const float* __restrict__ bk_,
              const float* __restrict__ bv_,
              u16* __restrict__ Qb, u16* __restrict__ Kb, u16* __restrict__ Vb)
{
    const int z = blockIdx.z;
    const u16* __restrict__ Wh = z == 0 ? Wh_q : (z == 1 ? Wh_k : Wh_v);
    const u16* __restrict__ Wl = z == 0 ? Wl_q : (z == 1 ? Wl_k : Wl_v);
    const float* __restrict__ bias = z == 0 ? bq_ : (z == 1 ? bk_ : bv_);
    u16* __restrict__ Ob = z == 0 ? Qb : (z == 1 ? Kb : Vb);
    const float oscale = (z == 0) ? 0.125f : 1.0f;

    __shared__ u16 Ah[128 * 40], Al[128 * 40], Bh[128 * 40], Bl[128 * 40];
    const int t = threadIdx.x;
    const int m0 = blockIdx.y * 128, n0 = blockIdx.x * 128;
    const int srow = t >> 1, scol = (t & 1) * 16;
    const int lane = t & 63, w = t >> 6, wm = w >> 1, wn = w & 1;
    const int lr = lane & 15, lg = lane >> 4;

    f32x4 acc[4][4] = {{{0.f, 0.f, 0.f, 0.f}}};
    for (int k0 = 0; k0 < HID; k0 += 32) {
        size_t ao = (size_t)(m0 + srow) * HID + k0 + scol;
        size_t bo = (size_t)(n0 + srow) * HID + k0 + scol;
        ush8 a0 = *(const ush8*)(Xh + ao), a1 = *(const ush8*)(Xh + ao + 8);
        ush8 a2 = *(const ush8*)(Xl + ao), a3 = *(const ush8*)(Xl + ao + 8);
        ush8 b0 = *(const ush8*)(Wh + bo), b1 = *(const ush8*)(Wh + bo + 8);
        ush8 b2 = *(const ush8*)(Wl + bo), b3 = *(const ush8*)(Wl + bo + 8);
        __syncthreads();
        *(ush8*)&Ah[srow * 40 + scol] = a0; *(ush8*)&Ah[srow * 40 + scol + 8] = a1;
        *(ush8*)&Al[srow * 40 + scol] = a2; *(ush8*)&Al[srow * 40 + scol + 8] = a3;
        *(ush8*)&Bh[srow * 40 + scol] = b0; *(ush8*)&Bh[srow * 40 + scol + 8] = b1;
        *(ush8*)&Bl[srow * 40 + scol] = b2; *(ush8*)&Bl[srow * 40 + scol + 8] = b3;
        __syncthreads();
        bf16x8 fbh[4], fbl[4];
#pragma unroll
        for (int ni = 0; ni < 4; ++ni) {
            fbh[ni] = *(const bf16x8*)&Bh[(wn * 64 + ni * 16 + lr) * 40 + lg * 8];
            fbl[ni] = *(const bf16x8*)&Bl[(wn * 64 + ni * 16 + lr) * 40 + lg * 8];
        }
#pragma unroll
        for (int mi = 0; mi < 4; ++mi) {
            bf16x8 fah = *(const bf16x8*)&Ah[(wm * 64 + mi * 16 + lr) * 40 + lg * 8];
            bf16x8 fal = *(const bf16x8*)&Al[(wm * 64 + mi * 16 + lr) * 40 + lg * 8];
#pragma unroll
            for (int ni = 0; ni < 4; ++ni) {
                f32x4 c = acc[mi][ni];
                c = __builtin_amdgcn_mfma_f32_16x16x32_bf16(fah, fbh[ni], c, 0, 0, 0);
                c = __builtin_amdgcn_mfma_f32_16x16x32_bf16(fah, fbl[ni], c, 0, 0, 0);
                c = __builtin_amdgcn_mfma_f32_16x16x32_bf16(fal, fbh[ni], c, 0, 0, 0);
                acc[mi][ni] = c;
            }
        }
    }
    const int hh = blockIdx.x * 2 + wn;
    float bv4[4];
#pragma unroll
    for (int ni = 0; ni < 4; ++ni) bv4[ni] = bias[n0 + wn * 64 + ni * 16 + lr];
#pragma unroll
    for (int mi = 0; mi < 4; ++mi)
#pragma unroll
        for (int r = 0; r < 4; ++r) {
            int m = m0 + wm * 64 + mi * 16 + lg * 4 + r;
            int b = m >> 11, s = m & 2047;
#pragma unroll
            for (int ni = 0; ni < 4; ++ni) {
                float v = (acc[mi][ni][r] + bv4[ni]) * oscale;
                Ob[((size_t)(b * NH + hh) * S + s) * HD + ni * 16 + lr] = f2bf(v);
            }
        }
}

// ---------------------------------------------------------------------------
// out = OH @ Wo^T + bo (split precision, fp32 out, NT stores). grid (8, 32)
// ---------------------------------------------------------------------------
__global__ __launch_bounds__(256)
void out_mfma(const u16* __restrict__ Xh, const u16* __restrict__ Xl,
              const u16* __restrict__ Wh, const u16* __restrict__ Wl,
              const float* __restrict__ bo_, float* __restrict__ Y)
{
    __shared__ u16 Ah[128 * 40], Al[128 * 40], Bh[128 * 40], Bl[128 * 40];
    const int t = threadIdx.x;
    const int m0 = blockIdx.y * 128, n0 = blockIdx.x * 128;
    const int srow = t >> 1, scol = (t & 1) * 16;
    const int lane = t & 63, w = t >> 6, wm = w >> 1, wn = w & 1;
    const int lr = lane & 15, lg = lane >> 4;

    f32x4 acc[4][4] = {{{0.f, 0.f, 0.f, 0.f}}};
    for (int k0 = 0; k0 < HID; k0 += 32) {
        size_t ao = (size_t)(m0 + srow) * HID + k0 + scol;
        size_t bo = (size_t)(n0 + srow) * HID + k0 + scol;
        ush8 a0 = *(const ush8*)(Xh + ao), a1 = *(const ush8*)(Xh + ao + 8);
        ush8 a2 = *(const ush8*)(Xl + ao), a3 = *(const ush8*)(Xl + ao + 8);
        ush8 b0 = *(const ush8*)(Wh + bo), b1 = *(const ush8*)(Wh + bo + 8);
        ush8 b2 = *(const ush8*)(Wl + bo), b3 = *(const ush8*)(Wl + bo + 8);
        __syncthreads();
        *(ush8*)&Ah[srow * 40 + scol] = a0; *(ush8*)&Ah[srow * 40 + scol + 8] = a1;
        *(ush8*)&Al[srow * 40 + scol] = a2; *(ush8*)&Al[srow * 40 + scol + 8] = a3;
        *(ush8*)&Bh[srow * 40 + scol] = b0; *(ush8*)&Bh[srow * 40 + scol + 8] = b1;
        *(ush8*)&Bl[srow * 40 + scol] = b2; *(ush8*)&Bl[srow * 40 + scol + 8] = b3;
        __syncthreads();
        bf16x8 fbh[4], fbl[4];
#pragma unroll
        for (int ni = 0; ni < 4; ++ni) {
            fbh[ni] = *(const bf16x8*)&Bh[(wn * 64 + ni * 16 + lr) * 40 + lg * 8];
            fbl[ni] = *(const bf16x8*)&Bl[(wn * 64 + ni * 16 + lr) * 40 + lg * 8];
        }
#pragma unroll
        for (int mi = 0; mi < 4; ++mi) {
            bf16x8 fah = *(const bf16x8*)&Ah[(wm * 64 + mi * 16 + lr) * 40 + lg * 8];
            bf16x8 fal = *(const bf16x8*)&Al[(wm * 64 + mi * 16 + lr) * 40 + lg * 8];
#pragma unroll
            for (int ni = 0; ni < 4; ++ni) {
                f32x4 c = acc[mi][ni];
                c = __builtin_amdgcn_mfma_f32_16x16x32_bf16(fah, fbh[ni], c, 0, 0, 0);
                c = __builtin_amdgcn_mfma_f32_16x16x32_bf16(fah, fbl[ni], c, 0, 0, 0);
                c = __builtin_amdgcn_mfma_f32_16x16x32_bf16(fal, fbh[ni], c, 0, 0, 0);
                acc[mi][ni] = c;
            }
        }
    }
    float bv4[4];
#pragma unroll
    for (int ni = 0; ni < 4; ++ni) bv4[ni] = bo_[n0 + wn * 64 + ni * 16 + lr];
#pragma unroll
    for (int mi = 0; mi < 4; ++mi)
#pragma unroll
        for (int r = 0; r < 4; ++r) {
            int m = m0 + wm * 64 + mi * 16 + lg * 4 + r;
#pragma unroll
            for (int ni = 0; ni < 4; ++ni)
                __builtin_nontemporal_store(acc[mi][ni][r] + bv4[ni],
                    &Y[(size_t)m * HID + n0 + wn * 64 + ni * 16 + lr]);
        }
}

// ---------------------------------------------------------------------------
// Fused attention (r8 structure + critical-path cuts):
//  - NT attn stores (don't evict dist/K/V from L2/L3)
//  - mask+rw*idf folded into LDS mb[2048] once per block
//  - dist prefetched one chunk ahead (T14)
//  - Q pre-scaled by 0.125 in qkv_mfma; qb = rw*idq per lane
// grid 512, 8 waves, q-tile 128; 1 barrier/chunk; P wave-local.
// ---------------------------------------------------------------------------
__global__ __launch_bounds__(512, 4)
void attn_pv(const u16* __restrict__ Qb, const u16* __restrict__ Kb,
             const u16* __restrict__ Vb,
             const int* __restrict__ dist, const float* __restrict__ idf,
             const int* __restrict__ amask, const float* __restrict__ semb,
             const float* __restrict__ rw,
             float* __restrict__ attn, u16* __restrict__ OHh, u16* __restrict__ OHl)
{
    __shared__ u16 Ks[2][64 * 72];    // K dbuf: [k 64][64 d + pad]
    __shared__ u16 Vts[2][64 * 72];   // V^T dbuf: [d 64][64 k + pad]
    __shared__ u16 Ps[128 * 72];      // P: [q-local 128][64 k + pad]
    __shared__ float SeH[51];
    __shared__ float mb[2048];        // mask ? rw*idf[k] : -inf

    const int n = blockIdx.x;
    const int xcd = n & 7, rest = n >> 3;      // rest 0..63
    const int h = rest & 15;
    const int pair = xcd * 4 + (rest >> 4);    // 0..31; same for all 16 h
    const int b = pair >> 4, qt = pair & 15;
    const int bh = b * NH + h, q0 = qt * 128;

    const int t = threadIdx.x, lane = t & 63, w = t >> 6;
    const int lr = lane & 15, lg = lane >> 4;
    const int q = q0 + w * 16 + lr;            // this lane's q row

    const int sr = t >> 3, sc = (t & 7) * 8;   // K staging: row, col (u16)

    const float rwv = rw[0];
    if (t < 51) SeH[t] = semb[t * NH + h];
    {   // fold mask + rw*idf into mb
        float4 ikv = *(const float4*)(idf + b * S + t * 4);
        int4   mv  = *(const int4*)(amask + b * S + t * 4);
        mb[t * 4 + 0] = mv.x ? rwv * ikv.x : -INFINITY;
        mb[t * 4 + 1] = mv.y ? rwv * ikv.y : -INFINITY;
        mb[t * 4 + 2] = mv.z ? rwv * ikv.z : -INFINITY;
        mb[t * 4 + 3] = mv.w ? rwv * ikv.w : -INFINITY;
    }

    // Q fragments direct from global (once; pre-scaled by 0.125)
    const u16* qrow = Qb + ((size_t)bh * S + q) * HD;
    bf16x8 qa0 = *(const bf16x8*)(qrow + lg * 8);
    bf16x8 qa1 = *(const bf16x8*)(qrow + 32 + lg * 8);

    const float qb = rwv * idf[b * S + q];
    const int*  dptr = dist + (size_t)(b * S + q) * S;
    const u16* kbase = Kb + (size_t)bh * S * HD;
    const u16* vbase = Vb + (size_t)bh * S * HD;

    // ---------------- pass A: online row stats ----------------
    float M = -INFINITY, Ssum = 0.f;
    int4 dcur[4];

    // prologue: stage K chunk 0, prefetch dist chunk 0
    *(ush8*)&Ks[0][sr * 72 + sc] = *(const ush8*)(kbase + (size_t)sr * HD + sc);
#pragma unroll
    for (int ni = 0; ni < 4; ++ni)
        dcur[ni] = *(const int4*)(dptr + ni * 16 + lg * 4);
    __syncthreads();

    for (int it = 0; it < 32; ++it) {
        const int k0 = it * 64;
        const int cur = it & 1;

        ush8 kreg; int4 dnx[4];
        if (it < 31) {   // T14: issue next-chunk loads early
            kreg = *(const ush8*)(kbase + (size_t)(k0 + 64 + sr) * HD + sc);
#pragma unroll
            for (int ni = 0; ni < 4; ++ni)
                dnx[ni] = *(const int4*)(dptr + k0 + 64 + ni * 16 + lg * 4);
        }

        f32x4 c2[4];
        __builtin_amdgcn_s_setprio(1);
#pragma unroll
        for (int ni = 0; ni < 4; ++ni) {
            bf16x8 kf0 = *(const bf16x8*)&Ks[cur][(ni * 16 + lr) * 72 + lg * 8];
            bf16x8 kf1 = *(const bf16x8*)&Ks[cur][(ni * 16 + lr) * 72 + 32 + lg * 8];
            f32x4 c = {0.f, 0.f, 0.f, 0.f};
            c = __builtin_amdgcn_mfma_f32_16x16x32_bf16(kf0, qa0, c, 0, 0, 0);
            c = __builtin_amdgcn_mfma_f32_16x16x32_bf16(kf1, qa1, c, 0, 0, 0);
            c2[ni] = c;
        }
        __builtin_amdgcn_s_setprio(0);

        float sc4[4][4];
        float chm = -INFINITY;
#pragma unroll
        for (int ni = 0; ni < 4; ++ni) {
            const int kb = k0 + ni * 16 + lg * 4;
            int dd[4] = {dcur[ni].x, dcur[ni].y, dcur[ni].z, dcur[ni].w};
#pragma unroll
            for (int r = 0; r < 4; ++r) {
                int dc = dd[r]; dc = dc < 0 ? 0 : (dc > 50 ? 50 : dc);
                float v = c2[ni][r] + SeH[dc] + qb + mb[kb + r];
                sc4[ni][r] = v;
                chm = fmaxf(chm, v);
            }
        }
        if (chm > -INFINITY) {
            float mn = fmaxf(M, chm);
            float s = 0.f;
#pragma unroll
            for (int ni = 0; ni < 4; ++ni)
#pragma unroll
                for (int r = 0; r < 4; ++r) s += __expf(sc4[ni][r] - mn);
            Ssum = Ssum * __expf(M - mn) + s;
            M = mn;
        }

        if (it < 31) {   // T14: write staged regs late
            *(ush8*)&Ks[cur ^ 1][sr * 72 + sc] = kreg;
#pragma unroll
            for (int ni = 0; ni < 4; ++ni) dcur[ni] = dnx[ni];
        }
        __syncthreads();
    }
    // merge the 4 lg lanes of this q row
#pragma unroll
    for (int off = 16; off <= 32; off <<= 1) {
        float Mo = __shfl_xor(M, off), So = __shfl_xor(Ssum, off);
        float mn = fmaxf(M, Mo);
        Ssum = Ssum * __expf(M - mn) + So * __expf(Mo - mn);
        M = mn;
    }
    const float Iv = 1.0f / Ssum;

    // ---------------- pass B: recompute, write attn (NT), PV ----------------
    float* aptr = attn + ((size_t)bh * S + q) * S;
    f32x4 oacc[4] = {{0.f,0.f,0.f,0.f},{0.f,0.f,0.f,0.f},
                     {0.f,0.f,0.f,0.f},{0.f,0.f,0.f,0.f}};

    // prologue: stage K+V chunk 0, prefetch dist chunk 0
    {
        *(ush8*)&Ks[0][sr * 72 + sc] = *(const ush8*)(kbase + (size_t)sr * HD + sc);
        ush8 v0 = *(const ush8*)(vbase + (size_t)lane * HD + w * 8);
#pragma unroll
        for (int j = 0; j < 8; ++j)
            Vts[0][(w * 8 + j) * 72 + lane] = v0[j];
#pragma unroll
        for (int ni = 0; ni < 4; ++ni)
            dcur[ni] = *(const int4*)(dptr + ni * 16 + lg * 4);
    }
    __syncthreads();

    for (int it = 0; it < 32; ++it) {
        const int k0 = it * 64;
        const int cur = it & 1;

        ush8 kreg, vreg; int4 dnx[4];
        if (it < 31) {   // T14: issue next-chunk loads early
            kreg = *(const ush8*)(kbase + (size_t)(k0 + 64 + sr) * HD + sc);
            vreg = *(const ush8*)(vbase + (size_t)(k0 + 64 + lane) * HD + w * 8);
#pragma unroll
            for (int ni = 0; ni < 4; ++ni)
                dnx[ni] = *(const int4*)(dptr + k0 + 64 + ni * 16 + lg * 4);
        }

        f32x4 c2[4];
        __builtin_amdgcn_s_setprio(1);
#pragma unroll
        for (int ni = 0; ni < 4; ++ni) {
            bf16x8 kf0 = *(const bf16x8*)&Ks[cur][(ni * 16 + lr) * 72 + lg * 8];
            bf16x8 kf1 = *(const bf16x8*)&Ks[cur][(ni * 16 + lr) * 72 + 32 + lg * 8];
            f32x4 c = {0.f, 0.f, 0.f, 0.f};
            c = __builtin_amdgcn_mfma_f32_16x16x32_bf16(kf0, qa0, c, 0, 0, 0);
            c = __builtin_amdgcn_mfma_f32_16x16x32_bf16(kf1, qa1, c, 0, 0, 0);
            c2[ni] = c;
        }
        __builtin_amdgcn_s_setprio(0);

#pragma unroll
        for (int ni = 0; ni < 4; ++ni) {
            const int kb = k0 + ni * 16 + lg * 4;
            int dd[4] = {dcur[ni].x, dcur[ni].y, dcur[ni].z, dcur[ni].w};
            float pp[4];
#pragma unroll
            for (int r = 0; r < 4; ++r) {
                int dc = dd[r]; dc = dc < 0 ? 0 : (dc > 50 ? 50 : dc);
                float v = c2[ni][r] + SeH[dc] + qb + mb[kb + r];
                pp[r] = __expf(v - M) * Iv;
            }
            f32x4 st = {pp[0], pp[1], pp[2], pp[3]};
            __builtin_nontemporal_store(st, (f32x4*)(aptr + kb));
            uint2 pk;
            pk.x = (u32)f2bf(pp[0]) | ((u32)f2bf(pp[1]) << 16);
            pk.y = (u32)f2bf(pp[2]) | ((u32)f2bf(pp[3]) << 16);
            *(uint2*)&Ps[(w * 16 + lr) * 72 + ni * 16 + lg * 4] = pk;
        }

        // PV: wave-local P rows (this wave wrote them; LDS ops in-order)
        bf16x8 pa0 = *(const bf16x8*)&Ps[(w * 16 + lr) * 72 + lg * 8];
        bf16x8 pa1 = *(const bf16x8*)&Ps[(w * 16 + lr) * 72 + 32 + lg * 8];
        __builtin_amdgcn_s_setprio(1);
#pragma unroll
        for (int ni = 0; ni < 4; ++ni) {
            bf16x8 vb0 = *(const bf16x8*)&Vts[cur][(ni * 16 + lr) * 72 + lg * 8];
            bf16x8 vb1 = *(const bf16x8*)&Vts[cur][(ni * 16 + lr) * 72 + 32 + lg * 8];
            oacc[ni] = __builtin_amdgcn_mfma_f32_16x16x32_bf16(pa0, vb0, oacc[ni], 0, 0, 0);
            oacc[ni] = __builtin_amdgcn_mfma_f32_16x16x32_bf16(pa1, vb1, oacc[ni], 0, 0, 0);
        }
        __builtin_amdgcn_s_setprio(0);

        if (it < 31) {   // T14: write staged regs late
            *(ush8*)&Ks[cur ^ 1][sr * 72 + sc] = kreg;
#pragma unroll
            for (int j = 0; j < 8; ++j)
                Vts[cur ^ 1][(w * 8 + j) * 72 + lane] = vreg[j];
#pragma unroll
            for (int ni = 0; ni < 4; ++ni) dcur[ni] = dnx[ni];
        }
        __syncthreads();
    }

    // OH epilogue: PV output is [q-local = lg*4+r][d = ni*16+lr]
#pragma unroll
    for (int r = 0; r < 4; ++r) {
        const int qq = q0 + w * 16 + lg * 4 + r;
#pragma unroll
        for (int ni = 0; ni < 4; ++ni) {
            float v = oacc[ni][r];
            u16 hi = f2bf(v);
            u16 lo = f2bf(v - bf2f(hi));
            size_t off = ((size_t)b * S + qq) * HID + h * HD + ni * 16 + lr;
            OHh[off] = hi;
            OHl[off] = lo;
        }
    }
}

// ---------------------------------------------------------------------------
extern "C" void kernel_launch(void* const* d_in, const int* in_sizes, int n_in,
                              void* d_out, int out_size, void* d_ws, size_t ws_size,
                              hipStream_t stream)
{
    const float* hs   = (const float*)d_in[0];
    const int*   dist = (const int*)d_in[1];
    const float* idf  = (const float*)d_in[2];
    const int*   am   = (const int*)d_in[3];
    const float* Wq   = (const float*)d_in[4];
    const float* bq   = (const float*)d_in[5];
    const float* Wk   = (const float*)d_in[6];
    const float* bk   = (const float*)d_in[7];
    const float* Wv   = (const float*)d_in[8];
    const float* bv   = (const float*)d_in[9];
    const float* Wo   = (const float*)d_in[10];
    const float* bo   = (const float*)d_in[11];
    const float* se   = (const float*)d_in[12];
    const float* rw   = (const float*)d_in[13];

    float* out  = (float*)d_out;
    float* attn = out + (size_t)2 * S * HID;

    // X hi/lo hide in the (not yet written) attn output region
    u16* Xh = (u16*)attn;
    u16* Xl = Xh + (size_t)4096 * 1024;

    // workspace layout
    u16* Qb  = (u16*)d_ws;
    u16* Kb  = Qb  + (size_t)BH * S * HD;
    u16* Vb  = Kb  + (size_t)BH * S * HD;
    u16* OHh = Vb  + (size_t)BH * S * HD;
    u16* OHl = OHh + (size_t)4096 * 1024;
    u16* Woh = OHl + (size_t)4096 * 1024;
    u16* Wol = Woh + (size_t)1024 * 1024;
    u16* Wqh = Wol + (size_t)1024 * 1024;
    u16* Wql = Wqh + (size_t)1024 * 1024;
    u16* Wkh = Wql + (size_t)1024 * 1024;
    u16* Wkl = Wkh + (size_t)1024 * 1024;
    u16* Wvh = Wkl + (size_t)1024 * 1024;
    u16* Wvl = Wvh + (size_t)1024 * 1024;

    dim3 blk(256);
    split_all<<<dim3(8192), blk, 0, stream>>>(hs, Wq, Wk, Wv, Wo,
                                              Xh, Xl, Wqh, Wql, Wkh, Wkl,
                                              Wvh, Wvl, Woh, Wol);
    qkv_mfma<<<dim3(8, 32, 3), blk, 0, stream>>>(Xh, Xl, Wqh, Wql, Wkh, Wkl,
                                                 Wvh, Wvl, bq, bk, bv, Qb, Kb, Vb);
    attn_pv<<<dim3(512), dim3(512), 0, stream>>>(Qb, Kb, Vb, dist, idf, am, se, rw,
                                                 attn, OHh, OHl);
    out_mfma<<<dim3(8, 32), blk, 0, stream>>>(OHh, OHl, Woh, Wol, bo, out);
}

// Round 10
// 415.256 us; speedup vs baseline: 1.6591x; 1.0364x over previous
//
#include <hip/hip_runtime.h>
#include <math.h>

#define S 2048
#define HID 1024
#define NH 16
#define HD 64
#define BH 32   // B * NH

typedef __attribute__((ext_vector_type(8))) short bf16x8;
typedef __attribute__((ext_vector_type(4))) float f32x4;
typedef __attribute__((ext_vector_type(8))) unsigned short ush8;
typedef unsigned short u16;
typedef unsigned int u32;

__device__ __forceinline__ u16 f2bf(float f) {
    unsigned u = __float_as_uint(f);
    u += 0x7fffu + ((u >> 16) & 1u);
    return (u16)(u >> 16);
}
__device__ __forceinline__ float bf2f(u16 h) {
    return __uint_as_float(((unsigned)h) << 16);
}

// ---------------------------------------------------------------------------
// Split fp32 -> (hi, lo) bf16 for X and all four weights in ONE launch.
// ---------------------------------------------------------------------------
__global__ __launch_bounds__(256)
void split_all(const float* __restrict__ X,  const float* __restrict__ Wq,
               const float* __restrict__ Wk, const float* __restrict__ Wv,
               const float* __restrict__ Wo,
               u16* __restrict__ Xh,  u16* __restrict__ Xl,
               u16* __restrict__ Wqh, u16* __restrict__ Wql,
               u16* __restrict__ Wkh, u16* __restrict__ Wkl,
               u16* __restrict__ Wvh, u16* __restrict__ Wvl,
               u16* __restrict__ Woh, u16* __restrict__ Wol)
{
    size_t i = (size_t)blockIdx.x * 256 + threadIdx.x;
    const float* s; u16* h; u16* l; size_t o;
    if (i < (size_t)(1u << 20)) { s = X; h = Xh; l = Xl; o = i; }
    else {
        size_t j = i - (1u << 20);
        int wsel = (int)(j >> 18); o = j & ((1u << 18) - 1);
        s = wsel == 0 ? Wq  : wsel == 1 ? Wk  : wsel == 2 ? Wv  : Wo;
        h = wsel == 0 ? Wqh : wsel == 1 ? Wkh : wsel == 2 ? Wvh : Woh;
        l = wsel == 0 ? Wql : wsel == 1 ? Wkl : wsel == 2 ? Wvl : Wol;
    }
    float4 v = ((const float4*)s)[o];
    ushort4 hv, lv;
#define SP(c, k) { unsigned u = __float_as_uint(v.c);                      \
                   unsigned hb = u & 0xffff0000u;                          \
                   float d = v.c - __uint_as_float(hb);                    \
                   hv.k = (u16)(u >> 16);                                  \
                   lv.k = (u16)(__float_as_uint(d) >> 16); }
    SP(x, x) SP(y, y) SP(z, z) SP(w, w)
#undef SP
    ((ushort4*)h)[o] = hv;
    ((ushort4*)l)[o] = lv;
}

// ---------------------------------------------------------------------------
// Split-precision MFMA GEMM: Y = X @ W^T + b. Output bf16 (b,h,s,d).
// Q is pre-scaled by 0.125 (exact power-of-2, same bf16 rounding).
// grid (8, 32, 3)
// ---------------------------------------------------------------------------
__global__ __launch_bounds__(256)
void qkv_mfma(const u16* __restrict__ Xh, const u16* __restrict__ Xl,
              const u16* __restrict__ Wh_q, const u16* __restrict__ Wl_q,
              const u16* __restrict__ Wh_k, const u16* __restrict__ Wl_k,
              const u16* __restrict__ Wh_v, const u16* __restrict__ Wl_v,
              const float* __restrict__ bq_, const float* __restrict__ bk_,
              const float* __restrict__ bv_,
              u16* __restrict__ Qb, u16* __restrict__ Kb, u16* __restrict__ Vb)
{
    const int z = blockIdx.z;
    const u16* __restrict__ Wh = z == 0 ? Wh_q : (z == 1 ? Wh_k : Wh_v);
    const u16* __restrict__ Wl = z == 0 ? Wl_q : (z == 1 ? Wl_k : Wl_v);
    const float* __restrict__ bias = z == 0 ? bq_ : (z == 1 ? bk_ : bv_);
    u16* __restrict__ Ob = z == 0 ? Qb : (z == 1 ? Kb : Vb);
    const float oscale = (z == 0) ? 0.125f : 1.0f;

    __shared__ u16 Ah[128 * 40], Al[128 * 40], Bh[128 * 40], Bl[128 * 40];
    const int t = threadIdx.x;
    const int m0 = blockIdx.y * 128, n0 = blockIdx.x * 128;
    const int srow = t >> 1, scol = (t & 1) * 16;
    const int lane = t & 63, w = t >> 6, wm = w >> 1, wn = w & 1;
    const int lr = lane & 15, lg = lane >> 4;

    f32x4 acc[4][4] = {{{0.f, 0.f, 0.f, 0.f}}};
    for (int k0 = 0; k0 < HID; k0 += 32) {
        size_t ao = (size_t)(m0 + srow) * HID + k0 + scol;
        size_t bo = (size_t)(n0 + srow) * HID + k0 + scol;
        ush8 a0 = *(const ush8*)(Xh + ao), a1 = *(const ush8*)(Xh + ao + 8);
        ush8 a2 = *(const ush8*)(Xl + ao), a3 = *(const ush8*)(Xl + ao + 8);
        ush8 b0 = *(const ush8*)(Wh + bo), b1 = *(const ush8*)(Wh + bo + 8);
        ush8 b2 = *(const ush8*)(Wl + bo), b3 = *(const ush8*)(Wl + bo + 8);
        __syncthreads();
        *(ush8*)&Ah[srow * 40 + scol] = a0; *(ush8*)&Ah[srow * 40 + scol + 8] = a1;
        *(ush8*)&Al[srow * 40 + scol] = a2; *(ush8*)&Al[srow * 40 + scol + 8] = a3;
        *(ush8*)&Bh[srow * 40 + scol] = b0; *(ush8*)&Bh[srow * 40 + scol + 8] = b1;
        *(ush8*)&Bl[srow * 40 + scol] = b2; *(ush8*)&Bl[srow * 40 + scol + 8] = b3;
        __syncthreads();
        bf16x8 fbh[4], fbl[4];
#pragma unroll
        for (int ni = 0; ni < 4; ++ni) {
            fbh[ni] = *(const bf16x8*)&Bh[(wn * 64 + ni * 16 + lr) * 40 + lg * 8];
            fbl[ni] = *(const bf16x8*)&Bl[(wn * 64 + ni * 16 + lr) * 40 + lg * 8];
        }
#pragma unroll
        for (int mi = 0; mi < 4; ++mi) {
            bf16x8 fah = *(const bf16x8*)&Ah[(wm * 64 + mi * 16 + lr) * 40 + lg * 8];
            bf16x8 fal = *(const bf16x8*)&Al[(wm * 64 + mi * 16 + lr) * 40 + lg * 8];
#pragma unroll
            for (int ni = 0; ni < 4; ++ni) {
                f32x4 c = acc[mi][ni];
                c = __builtin_amdgcn_mfma_f32_16x16x32_bf16(fah, fbh[ni], c, 0, 0, 0);
                c = __builtin_amdgcn_mfma_f32_16x16x32_bf16(fah, fbl[ni], c, 0, 0, 0);
                c = __builtin_amdgcn_mfma_f32_16x16x32_bf16(fal, fbh[ni], c, 0, 0, 0);
                acc[mi][ni] = c;
            }
        }
    }
    const int hh = blockIdx.x * 2 + wn;
    float bv4[4];
#pragma unroll
    for (int ni = 0; ni < 4; ++ni) bv4[ni] = bias[n0 + wn * 64 + ni * 16 + lr];
#pragma unroll
    for (int mi = 0; mi < 4; ++mi)
#pragma unroll
        for (int r = 0; r < 4; ++r) {
            int m = m0 + wm * 64 + mi * 16 + lg * 4 + r;
            int b = m >> 11, s = m & 2047;
#pragma unroll
            for (int ni = 0; ni < 4; ++ni) {
                float v = (acc[mi][ni][r] + bv4[ni]) * oscale;
                Ob[((size_t)(b * NH + hh) * S + s) * HD + ni * 16 + lr] = f2bf(v);
            }
        }
}

// ---------------------------------------------------------------------------
// out = OH @ Wo^T + bo (split precision, fp32 out, NT stores). grid (8, 32)
// ---------------------------------------------------------------------------
__global__ __launch_bounds__(256)
void out_mfma(const u16* __restrict__ Xh, const u16* __restrict__ Xl,
              const u16* __restrict__ Wh, const u16* __restrict__ Wl,
              const float* __restrict__ bo_, float* __restrict__ Y)
{
    __shared__ u16 Ah[128 * 40], Al[128 * 40], Bh[128 * 40], Bl[128 * 40];
    const int t = threadIdx.x;
    const int m0 = blockIdx.y * 128, n0 = blockIdx.x * 128;
    const int srow = t >> 1, scol = (t & 1) * 16;
    const int lane = t & 63, w = t >> 6, wm = w >> 1, wn = w & 1;
    const int lr = lane & 15, lg = lane >> 4;

    f32x4 acc[4][4] = {{{0.f, 0.f, 0.f, 0.f}}};
    for (int k0 = 0; k0 < HID; k0 += 32) {
        size_t ao = (size_t)(m0 + srow) * HID + k0 + scol;
        size_t bo = (size_t)(n0 + srow) * HID + k0 + scol;
        ush8 a0 = *(const ush8*)(Xh + ao), a1 = *(const ush8*)(Xh + ao + 8);
        ush8 a2 = *(const ush8*)(Xl + ao), a3 = *(const ush8*)(Xl + ao + 8);
        ush8 b0 = *(const ush8*)(Wh + bo), b1 = *(const ush8*)(Wh + bo + 8);
        ush8 b2 = *(const ush8*)(Wl + bo), b3 = *(const ush8*)(Wl + bo + 8);
        __syncthreads();
        *(ush8*)&Ah[srow * 40 + scol] = a0; *(ush8*)&Ah[srow * 40 + scol + 8] = a1;
        *(ush8*)&Al[srow * 40 + scol] = a2; *(ush8*)&Al[srow * 40 + scol + 8] = a3;
        *(ush8*)&Bh[srow * 40 + scol] = b0; *(ush8*)&Bh[srow * 40 + scol + 8] = b1;
        *(ush8*)&Bl[srow * 40 + scol] = b2; *(ush8*)&Bl[srow * 40 + scol + 8] = b3;
        __syncthreads();
        bf16x8 fbh[4], fbl[4];
#pragma unroll
        for (int ni = 0; ni < 4; ++ni) {
            fbh[ni] = *(const bf16x8*)&Bh[(wn * 64 + ni * 16 + lr) * 40 + lg * 8];
            fbl[ni] = *(const bf16x8*)&Bl[(wn * 64 + ni * 16 + lr) * 40 + lg * 8];
        }
#pragma unroll
        for (int mi = 0; mi < 4; ++mi) {
            bf16x8 fah = *(const bf16x8*)&Ah[(wm * 64 + mi * 16 + lr) * 40 + lg * 8];
            bf16x8 fal = *(const bf16x8*)&Al[(wm * 64 + mi * 16 + lr) * 40 + lg * 8];
#pragma unroll
            for (int ni = 0; ni < 4; ++ni) {
                f32x4 c = acc[mi][ni];
                c = __builtin_amdgcn_mfma_f32_16x16x32_bf16(fah, fbh[ni], c, 0, 0, 0);
                c = __builtin_amdgcn_mfma_f32_16x16x32_bf16(fah, fbl[ni], c, 0, 0, 0);
                c = __builtin_amdgcn_mfma_f32_16x16x32_bf16(fal, fbh[ni], c, 0, 0, 0);
                acc[mi][ni] = c;
            }
        }
    }
    float bv4[4];
#pragma unroll
    for (int ni = 0; ni < 4; ++ni) bv4[ni] = bo_[n0 + wn * 64 + ni * 16 + lr];
#pragma unroll
    for (int mi = 0; mi < 4; ++mi)
#pragma unroll
        for (int r = 0; r < 4; ++r) {
            int m = m0 + wm * 64 + mi * 16 + lg * 4 + r;
#pragma unroll
            for (int ni = 0; ni < 4; ++ni)
                __builtin_nontemporal_store(acc[mi][ni][r] + bv4[ni],
                    &Y[(size_t)m * HID + n0 + wn * 64 + ni * 16 + lr]);
        }
}

// ---------------------------------------------------------------------------
// Fused attention (r9 + pass-A 4-buffer pipeline):
//  Pass A: K rotates through 4 LDS buffers (Vts/Ps area is dead in pass A),
//    prefetch distance 2 chunks, barrier every 2 iterations (16 total).
//  Pass B: unchanged r9 (K/V dbuf, 1 barrier/chunk, NT attn stores).
// grid 512, 8 waves, q-tile 128; P wave-local.
// ---------------------------------------------------------------------------
__global__ __launch_bounds__(512, 4)
void attn_pv(const u16* __restrict__ Qb, const u16* __restrict__ Kb,
             const u16* __restrict__ Vb,
             const int* __restrict__ dist, const float* __restrict__ idf,
             const int* __restrict__ amask, const float* __restrict__ semb,
             const float* __restrict__ rw,
             float* __restrict__ attn, u16* __restrict__ OHh, u16* __restrict__ OHl)
{
    __shared__ u16 KV[4][64 * 72];    // A: K 4-buf rotation; B: [0,1]=K dbuf, [2,3]=V^T dbuf
    __shared__ u16 Ps[128 * 72];      // P: [q-local 128][64 k + pad]
    __shared__ float SeH[51];
    __shared__ float mb[2048];        // mask ? rw*idf[k] : -inf

    const int n = blockIdx.x;
    const int xcd = n & 7, rest = n >> 3;      // rest 0..63
    const int h = rest & 15;
    const int pair = xcd * 4 + (rest >> 4);    // 0..31; same for all 16 h
    const int b = pair >> 4, qt = pair & 15;
    const int bh = b * NH + h, q0 = qt * 128;

    const int t = threadIdx.x, lane = t & 63, w = t >> 6;
    const int lr = lane & 15, lg = lane >> 4;
    const int q = q0 + w * 16 + lr;            // this lane's q row

    const int sr = t >> 3, sc = (t & 7) * 8;   // K staging: row, col (u16)

    const float rwv = rw[0];
    if (t < 51) SeH[t] = semb[t * NH + h];
    {   // fold mask + rw*idf into mb
        float4 ikv = *(const float4*)(idf + b * S + t * 4);
        int4   mv  = *(const int4*)(amask + b * S + t * 4);
        mb[t * 4 + 0] = mv.x ? rwv * ikv.x : -INFINITY;
        mb[t * 4 + 1] = mv.y ? rwv * ikv.y : -INFINITY;
        mb[t * 4 + 2] = mv.z ? rwv * ikv.z : -INFINITY;
        mb[t * 4 + 3] = mv.w ? rwv * ikv.w : -INFINITY;
    }

    // Q fragments direct from global (once; pre-scaled by 0.125)
    const u16* qrow = Qb + ((size_t)bh * S + q) * HD;
    bf16x8 qa0 = *(const bf16x8*)(qrow + lg * 8);
    bf16x8 qa1 = *(const bf16x8*)(qrow + 32 + lg * 8);

    const float qb = rwv * idf[b * S + q];
    const int*  dptr = dist + (size_t)(b * S + q) * S;
    const u16* kbase = Kb + (size_t)bh * S * HD;
    const u16* vbase = Vb + (size_t)bh * S * HD;

    // ---------------- pass A: online row stats, 4-buf K pipeline ------------
    float M = -INFINITY, Ssum = 0.f;
    int4 dcur[4];

    // prologue: stage K chunks 0,1; prefetch dist chunk 0
    *(ush8*)&KV[0][sr * 72 + sc] = *(const ush8*)(kbase + (size_t)sr * HD + sc);
    *(ush8*)&KV[1][sr * 72 + sc] = *(const ush8*)(kbase + (size_t)(64 + sr) * HD + sc);
#pragma unroll
    for (int ni = 0; ni < 4; ++ni)
        dcur[ni] = *(const int4*)(dptr + ni * 16 + lg * 4);
    __syncthreads();

    for (int it = 0; it < 32; ++it) {
        const int k0 = it * 64;
        const int cur = it & 3;

        ush8 kreg; int4 dnx[4];
        if (it < 30)   // prefetch K chunk it+2 (2-deep)
            kreg = *(const ush8*)(kbase + (size_t)(k0 + 128 + sr) * HD + sc);
        if (it < 31) { // prefetch dist chunk it+1 (1-deep)
#pragma unroll
            for (int ni = 0; ni < 4; ++ni)
                dnx[ni] = *(const int4*)(dptr + k0 + 64 + ni * 16 + lg * 4);
        }

        f32x4 c2[4];
        __builtin_amdgcn_s_setprio(1);
#pragma unroll
        for (int ni = 0; ni < 4; ++ni) {
            bf16x8 kf0 = *(const bf16x8*)&KV[cur][(ni * 16 + lr) * 72 + lg * 8];
            bf16x8 kf1 = *(const bf16x8*)&KV[cur][(ni * 16 + lr) * 72 + 32 + lg * 8];
            f32x4 c = {0.f, 0.f, 0.f, 0.f};
            c = __builtin_amdgcn_mfma_f32_16x16x32_bf16(kf0, qa0, c, 0, 0, 0);
            c = __builtin_amdgcn_mfma_f32_16x16x32_bf16(kf1, qa1, c, 0, 0, 0);
            c2[ni] = c;
        }
        __builtin_amdgcn_s_setprio(0);

        float sc4[4][4];
        float chm = -INFINITY;
#pragma unroll
        for (int ni = 0; ni < 4; ++ni) {
            const int kb = k0 + ni * 16 + lg * 4;
            int dd[4] = {dcur[ni].x, dcur[ni].y, dcur[ni].z, dcur[ni].w};
#pragma unroll
            for (int r = 0; r < 4; ++r) {
                int dc = dd[r]; dc = dc < 0 ? 0 : (dc > 50 ? 50 : dc);
                float v = c2[ni][r] + SeH[dc] + qb + mb[kb + r];
                sc4[ni][r] = v;
                chm = fmaxf(chm, v);
            }
        }
        if (chm > -INFINITY) {
            float mn = fmaxf(M, chm);
            float s = 0.f;
#pragma unroll
            for (int ni = 0; ni < 4; ++ni)
#pragma unroll
                for (int r = 0; r < 4; ++r) s += __expf(sc4[ni][r] - mn);
            Ssum = Ssum * __expf(M - mn) + s;
            M = mn;
        }

        if (it < 30)
            *(ush8*)&KV[(it + 2) & 3][sr * 72 + sc] = kreg;
        if (it < 31) {
#pragma unroll
            for (int ni = 0; ni < 4; ++ni) dcur[ni] = dnx[ni];
        }
        if ((it & 1) && it < 31) __syncthreads();
    }
    // merge the 4 lg lanes of this q row
#pragma unroll
    for (int off = 16; off <= 32; off <<= 1) {
        float Mo = __shfl_xor(M, off), So = __shfl_xor(Ssum, off);
        float mn = fmaxf(M, Mo);
        Ssum = Ssum * __expf(M - mn) + So * __expf(Mo - mn);
        M = mn;
    }
    const float Iv = 1.0f / Ssum;
    __syncthreads();   // pass A fully done before pass B restages LDS

    // ---------------- pass B: recompute, write attn (NT), PV ----------------
    float* aptr = attn + ((size_t)bh * S + q) * S;
    f32x4 oacc[4] = {{0.f,0.f,0.f,0.f},{0.f,0.f,0.f,0.f},
                     {0.f,0.f,0.f,0.f},{0.f,0.f,0.f,0.f}};

    // prologue: stage K+V chunk 0, prefetch dist chunk 0
    {
        *(ush8*)&KV[0][sr * 72 + sc] = *(const ush8*)(kbase + (size_t)sr * HD + sc);
        ush8 v0 = *(const ush8*)(vbase + (size_t)lane * HD + w * 8);
#pragma unroll
        for (int j = 0; j < 8; ++j)
            KV[2][(w * 8 + j) * 72 + lane] = v0[j];
#pragma unroll
        for (int ni = 0; ni < 4; ++ni)
            dcur[ni] = *(const int4*)(dptr + ni * 16 + lg * 4);
    }
    __syncthreads();

    for (int it = 0; it < 32; ++it) {
        const int k0 = it * 64;
        const int cur = it & 1;

        ush8 kreg, vreg; int4 dnx[4];
        if (it < 31) {   // T14: issue next-chunk loads early
            kreg = *(const ush8*)(kbase + (size_t)(k0 + 64 + sr) * HD + sc);
            vreg = *(const ush8*)(vbase + (size_t)(k0 + 64 + lane) * HD + w * 8);
#pragma unroll
            for (int ni = 0; ni < 4; ++ni)
                dnx[ni] = *(const int4*)(dptr + k0 + 64 + ni * 16 + lg * 4);
        }

        f32x4 c2[4];
        __builtin_amdgcn_s_setprio(1);
#pragma unroll
        for (int ni = 0; ni < 4; ++ni) {
            bf16x8 kf0 = *(const bf16x8*)&KV[cur][(ni * 16 + lr) * 72 + lg * 8];
            bf16x8 kf1 = *(const bf16x8*)&KV[cur][(ni * 16 + lr) * 72 + 32 + lg * 8];
            f32x4 c = {0.f, 0.f, 0.f, 0.f};
            c = __builtin_amdgcn_mfma_f32_16x16x32_bf16(kf0, qa0, c, 0, 0, 0);
            c = __builtin_amdgcn_mfma_f32_16x16x32_bf16(kf1, qa1, c, 0, 0, 0);
            c2[ni] = c;
        }
        __builtin_amdgcn_s_setprio(0);

#pragma unroll
        for (int ni = 0; ni < 4; ++ni) {
            const int kb = k0 + ni * 16 + lg * 4;
            int dd[4] = {dcur[ni].x, dcur[ni].y, dcur[ni].z, dcur[ni].w};
            float pp[4];
#pragma unroll
            for (int r = 0; r < 4; ++r) {
                int dc = dd[r]; dc = dc < 0 ? 0 : (dc > 50 ? 50 : dc);
                float v = c2[ni][r] + SeH[dc] + qb + mb[kb + r];
                pp[r] = __expf(v - M) * Iv;
            }
            f32x4 st = {pp[0], pp[1], pp[2], pp[3]};
            __builtin_nontemporal_store(st, (f32x4*)(aptr + kb));
            uint2 pk;
            pk.x = (u32)f2bf(pp[0]) | ((u32)f2bf(pp[1]) << 16);
            pk.y = (u32)f2bf(pp[2]) | ((u32)f2bf(pp[3]) << 16);
            *(uint2*)&Ps[(w * 16 + lr) * 72 + ni * 16 + lg * 4] = pk;
        }

        // PV: wave-local P rows (this wave wrote them; LDS ops in-order)
        bf16x8 pa0 = *(const bf16x8*)&Ps[(w * 16 + lr) * 72 + lg * 8];
        bf16x8 pa1 = *(const bf16x8*)&Ps[(w * 16 + lr) * 72 + 32 + lg * 8];
        __builtin_amdgcn_s_setprio(1);
#pragma unroll
        for (int ni = 0; ni < 4; ++ni) {
            bf16x8 vb0 = *(const bf16x8*)&KV[2 + cur][(ni * 16 + lr) * 72 + lg * 8];
            bf16x8 vb1 = *(const bf16x8*)&KV[2 + cur][(ni * 16 + lr) * 72 + 32 + lg * 8];
            oacc[ni] = __builtin_amdgcn_mfma_f32_16x16x32_bf16(pa0, vb0, oacc[ni], 0, 0, 0);
            oacc[ni] = __builtin_amdgcn_mfma_f32_16x16x32_bf16(pa1, vb1, oacc[ni], 0, 0, 0);
        }
        __builtin_amdgcn_s_setprio(0);

        if (it < 31) {   // T14: write staged regs late
            *(ush8*)&KV[cur ^ 1][sr * 72 + sc] = kreg;
#pragma unroll
            for (int j = 0; j < 8; ++j)
                KV[2 + (cur ^ 1)][(w * 8 + j) * 72 + lane] = vreg[j];
#pragma unroll
            for (int ni = 0; ni < 4; ++ni) dcur[ni] = dnx[ni];
        }
        __syncthreads();
    }

    // OH epilogue: PV output is [q-local = lg*4+r][d = ni*16+lr]
#pragma unroll
    for (int r = 0; r < 4; ++r) {
        const int qq = q0 + w * 16 + lg * 4 + r;
#pragma unroll
        for (int ni = 0; ni < 4; ++ni) {
            float v = oacc[ni][r];
            u16 hi = f2bf(v);
            u16 lo = f2bf(v - bf2f(hi));
            size_t off = ((size_t)b * S + qq) * HID + h * HD + ni * 16 + lr;
            OHh[off] = hi;
            OHl[off] = lo;
        }
    }
}

// ---------------------------------------------------------------------------
extern "C" void kernel_launch(void* const* d_in, const int* in_sizes, int n_in,
                              void* d_out, int out_size, void* d_ws, size_t ws_size,
                              hipStream_t stream)
{
    const float* hs   = (const float*)d_in[0];
    const int*   dist = (const int*)d_in[1];
    const float* idf  = (const float*)d_in[2];
    const int*   am   = (const int*)d_in[3];
    const float* Wq   = (const float*)d_in[4];
    const float* bq   = (const float*)d_in[5];
    const float* Wk   = (const float*)d_in[6];
    const float* bk   = (const float*)d_in[7];
    const float* Wv   = (const float*)d_in[8];
    const float* bv   = (const float*)d_in[9];
    const float* Wo   = (const float*)d_in[10];
    const float* bo   = (const float*)d_in[11];
    const float* se   = (const float*)d_in[12];
    const float* rw   = (const float*)d_in[13];

    float* out  = (float*)d_out;
    float* attn = out + (size_t)2 * S * HID;

    // X hi/lo hide in the (not yet written) attn output region
    u16* Xh = (u16*)attn;
    u16* Xl = Xh + (size_t)4096 * 1024;

    // workspace layout
    u16* Qb  = (u16*)d_ws;
    u16* Kb  = Qb  + (size_t)BH * S * HD;
    u16* Vb  = Kb  + (size_t)BH * S * HD;
    u16* OHh = Vb  + (size_t)BH * S * HD;
    u16* OHl = OHh + (size_t)4096 * 1024;
    u16* Woh = OHl + (size_t)4096 * 1024;
    u16* Wol = Woh + (size_t)1024 * 1024;
    u16* Wqh = Wol + (size_t)1024 * 1024;
    u16* Wql = Wqh + (size_t)1024 * 1024;
    u16* Wkh = Wql + (size_t)1024 * 1024;
    u16* Wkl = Wkh + (size_t)1024 * 1024;
    u16* Wvh = Wkl + (size_t)1024 * 1024;
    u16* Wvl = Wvh + (size_t)1024 * 1024;

    dim3 blk(256);
    split_all<<<dim3(8192), blk, 0, stream>>>(hs, Wq, Wk, Wv, Wo,
                                              Xh, Xl, Wqh, Wql, Wkh, Wkl,
                                              Wvh, Wvl, Woh, Wol);
    qkv_mfma<<<dim3(8, 32, 3), blk, 0, stream>>>(Xh, Xl, Wqh, Wql, Wkh, Wkl,
                                                 Wvh, Wvl, bq, bk, bv, Qb, Kb, Vb);
    attn_pv<<<dim3(512), dim3(512), 0, stream>>>(Qb, Kb, Vb, dist, idf, am, se, rw,
                                                 attn, OHh, OHl);
    out_mfma<<<dim3(8, 32), blk, 0, stream>>>(OHh, OHl, Woh, Wol, bo, out);
}